// Round 1
// baseline (546.182 us; speedup 1.0000x reference)
//
#include <hip/hip_runtime.h>
#include <math.h>

// GaussianGenerator: 3x GMMConv (dense radius graph per 1024 graphs) + 2 MLPs.
// All fp32. One workgroup per graph for convs; wave-per-row MLPs.

__device__ __forceinline__ float eluf(float v) { return v > 0.f ? v : __expf(v) - 1.f; }

// ---------------- conv1: n=5, fin=64, K=25, out=160 ----------------
__global__ __launch_bounds__(256) void conv1_kernel(
    const float* __restrict__ x, const float* __restrict__ pos,
    const float* __restrict__ g, const float* __restrict__ mu, const float* __restrict__ sig,
    const float* __restrict__ root, const float* __restrict__ bias,
    float* __restrict__ xout)
{
  const int b = blockIdx.x, tid = threadIdx.x;
  __shared__ float s_pos[5][2];
  __shared__ __align__(16) float s_x[5][64];
  __shared__ float s_w[5][5][25];                 // [s][t][k]
  __shared__ __align__(16) float s_wx[5][1600];   // [t][k*64+i]
  __shared__ float s_ms[25][4];                   // mu0 mu1 inv0 inv1
  __shared__ float s_deg[5];

  if (tid < 10) (&s_pos[0][0])[tid] = pos[b * 10 + tid];
  for (int e = tid; e < 320; e += 256) (&s_x[0][0])[e] = x[b * 320 + e];
  if (tid < 50) {
    int k = tid >> 1, d = tid & 1;
    s_ms[k][d] = mu[tid];
    float sg = sig[tid];
    s_ms[k][2 + d] = 1.f / (sg * sg + 1e-15f);
  }
  __syncthreads();

  for (int e = tid; e < 625; e += 256) {
    int s = e / 125, r = e % 125, t = r / 25, k = r % 25;
    float d0 = s_pos[t][0] - s_pos[s][0];
    float d1 = s_pos[t][1] - s_pos[s][1];
    float e0 = d0 + 1e-12f, e1 = d1 + 1e-12f;
    float dist = sqrtf(e0 * e0 + e1 * e1);
    bool m = (dist < 0.5f) && (s != t);
    float q0 = 2.f * d0 + 0.5f - s_ms[k][0];
    float q1 = 2.f * d1 + 0.5f - s_ms[k][1];
    float ex = __expf(-0.5f * (q0 * q0 * s_ms[k][2] + q1 * q1 * s_ms[k][3]));
    s_w[s][t][k] = m ? ex : 0.f;
  }
  if (tid < 5) {
    int t = tid, c = 0;
    for (int s = 0; s < 5; ++s) {
      if (s == t) continue;
      float d0 = s_pos[t][0] - s_pos[s][0] + 1e-12f;
      float d1 = s_pos[t][1] - s_pos[s][1] + 1e-12f;
      if (sqrtf(d0 * d0 + d1 * d1) < 0.5f) ++c;
    }
    s_deg[t] = (float)(c < 1 ? 1 : c);
  }
  __syncthreads();

  // wx[t][k*64+i] = (1/deg[t]) * sum_s w[s][t][k] * x[s][i]
  for (int e = tid; e < 8000; e += 256) {
    int t = e / 1600, r = e % 1600, k = r / 64, i = r % 64;
    float a = 0.f;
    #pragma unroll
    for (int s = 0; s < 5; ++s) a += s_w[s][t][k] * s_x[s][i];
    s_wx[t][r] = a / s_deg[t];
  }
  __syncthreads();

  if (tid < 160) {
    const int o = tid;
    float acc[5] = {0.f, 0.f, 0.f, 0.f, 0.f};
    for (int k = 0; k < 25; ++k) {
      const float* gk = g + k * 160 + o;
      for (int i = 0; i < 64; i += 4) {
        float gv0 = gk[(i + 0) * 4000];
        float gv1 = gk[(i + 1) * 4000];
        float gv2 = gk[(i + 2) * 4000];
        float gv3 = gk[(i + 3) * 4000];
        #pragma unroll
        for (int t = 0; t < 5; ++t) {
          float4 w4 = *(const float4*)&s_wx[t][k * 64 + i];
          acc[t] += w4.x * gv0 + w4.y * gv1 + w4.z * gv2 + w4.w * gv3;
        }
      }
    }
    // + x @ root + bias, elu
    float racc[5] = {0.f, 0.f, 0.f, 0.f, 0.f};
    for (int i = 0; i < 64; ++i) {
      float rv = root[i * 160 + o];
      #pragma unroll
      for (int t = 0; t < 5; ++t) racc[t] += s_x[t][i] * rv;
    }
    float bo = bias[o];
    #pragma unroll
    for (int t = 0; t < 5; ++t)
      xout[(b * 5 + t) * 160 + o] = eluf(acc[t] + racc[t] + bo);
  }
}

// ---------------- conv2: n=25, fin=32, K=25, out=48 ----------------
__global__ __launch_bounds__(256) void conv2_kernel(
    const float* __restrict__ x, const float* __restrict__ pos,
    const float* __restrict__ g, const float* __restrict__ mu, const float* __restrict__ sig,
    const float* __restrict__ root, const float* __restrict__ bias,
    float* __restrict__ xout)
{
  const int b = blockIdx.x, tid = threadIdx.x;
  __shared__ float s_pos[25][2];
  __shared__ __align__(16) float s_x[25][32];
  __shared__ float s_ms[25][4];
  __shared__ float s_ideg[25];
  __shared__ __align__(16) float s_wx[25][416];   // [t][kk*32+i], K split 13+12

  if (tid < 50) (&s_pos[0][0])[tid] = pos[b * 50 + tid];
  for (int e = tid; e < 800; e += 256) (&s_x[0][0])[e] = x[b * 800 + e];
  if (tid < 50) {
    int k = tid >> 1, d = tid & 1;
    s_ms[k][d] = mu[tid];
    float sg = sig[tid];
    s_ms[k][2 + d] = 1.f / (sg * sg + 1e-15f);
  }
  __syncthreads();
  if (tid < 25) {
    int t = tid, c = 0;
    for (int s = 0; s < 25; ++s) {
      if (s == t) continue;
      float d0 = s_pos[t][0] - s_pos[s][0] + 1e-12f;
      float d1 = s_pos[t][1] - s_pos[s][1] + 1e-12f;
      if (sqrtf(d0 * d0 + d1 * d1) < 0.5f) ++c;
    }
    s_ideg[t] = 1.f / (float)(c < 1 ? 1 : c);
  }
  __syncthreads();

  const int o = tid % 48, tg = tid / 48, t0 = tg * 5;
  float acc[5] = {0.f, 0.f, 0.f, 0.f, 0.f};

  for (int half = 0; half < 2; ++half) {
    const int kbase = half ? 13 : 0;
    const int NK = half ? 12 : 13;
    // phase A: wx[t][kk*32+i] = (1/deg[t]) * sum_s w(s,t,k) * x[s][i]
    for (int e = tid; e < 25 * NK; e += 256) {
      int t = e / NK, kk = e % NK, k = kbase + kk;
      float mu0 = s_ms[k][0], mu1 = s_ms[k][1], iv0 = s_ms[k][2], iv1 = s_ms[k][3];
      float pt0 = s_pos[t][0], pt1 = s_pos[t][1];
      float wcol[25];
      for (int s = 0; s < 25; ++s) {
        float d0 = pt0 - s_pos[s][0], d1 = pt1 - s_pos[s][1];
        float e0 = d0 + 1e-12f, e1 = d1 + 1e-12f;
        float dist = sqrtf(e0 * e0 + e1 * e1);
        bool m = (dist < 0.5f) && (s != t);
        float q0 = 2.f * d0 + 0.5f - mu0, q1 = 2.f * d1 + 0.5f - mu1;
        float ex = __expf(-0.5f * (q0 * q0 * iv0 + q1 * q1 * iv1));
        wcol[s] = m ? ex : 0.f;
      }
      float a[32];
      #pragma unroll
      for (int i = 0; i < 32; ++i) a[i] = 0.f;
      for (int s = 0; s < 25; ++s) {
        float wv = wcol[s];
        #pragma unroll
        for (int i = 0; i < 32; i += 4) {
          float4 xv = *(const float4*)&s_x[s][i];
          a[i] += wv * xv.x; a[i + 1] += wv * xv.y; a[i + 2] += wv * xv.z; a[i + 3] += wv * xv.w;
        }
      }
      float invd = s_ideg[t];
      #pragma unroll
      for (int i = 0; i < 32; i += 4) {
        float4 st; st.x = a[i] * invd; st.y = a[i + 1] * invd; st.z = a[i + 2] * invd; st.w = a[i + 3] * invd;
        *(float4*)&s_wx[t][kk * 32 + i] = st;
      }
    }
    __syncthreads();
    // phase B: acc[j] += sum_{kk,i} wx[t0+j][kk*32+i] * g[i*1200 + k*48 + o]
    if (tid < 240) {
      for (int kk = 0; kk < NK; ++kk) {
        const float* gp = g + (kbase + kk) * 48 + o;
        for (int i = 0; i < 32; i += 4) {
          float gv0 = gp[(i + 0) * 1200];
          float gv1 = gp[(i + 1) * 1200];
          float gv2 = gp[(i + 2) * 1200];
          float gv3 = gp[(i + 3) * 1200];
          #pragma unroll
          for (int j = 0; j < 5; ++j) {
            float4 w4 = *(const float4*)&s_wx[t0 + j][kk * 32 + i];
            acc[j] += w4.x * gv0 + w4.y * gv1 + w4.z * gv2 + w4.w * gv3;
          }
        }
      }
    }
    __syncthreads();
  }

  if (tid < 240) {
    float racc[5] = {0.f, 0.f, 0.f, 0.f, 0.f};
    for (int i = 0; i < 32; ++i) {
      float rv = root[i * 48 + o];
      #pragma unroll
      for (int j = 0; j < 5; ++j) racc[j] += s_x[t0 + j][i] * rv;
    }
    float bo = bias[o];
    #pragma unroll
    for (int j = 0; j < 5; ++j)
      xout[(b * 25 + t0 + j) * 48 + o] = eluf(acc[j] + racc[j] + bo);
  }
}

// ---------------- conv3: n=75, fin=16, K=25, out=1, tanh ----------------
__global__ __launch_bounds__(256) void conv3_kernel(
    const float* __restrict__ x, const float* __restrict__ pos,
    const float* __restrict__ g, const float* __restrict__ mu, const float* __restrict__ sig,
    const float* __restrict__ root, const float* __restrict__ bias,
    float* __restrict__ xout)
{
  const int b = blockIdx.x, tid = threadIdx.x;
  __shared__ float s_pos[75][2];
  __shared__ float s_x[75][16];
  __shared__ float s_g3[400];        // g[i*25+k]
  __shared__ float s_ms[25][4];
  __shared__ float s_ideg[75];
  __shared__ float s_xm[75][25];
  __shared__ float s_part[75][26];   // padded
  __shared__ float s_r3[16];

  if (tid < 150) (&s_pos[0][0])[tid] = pos[b * 150 + tid];
  for (int e = tid; e < 1200; e += 256) (&s_x[0][0])[e] = x[b * 1200 + e];
  for (int e = tid; e < 400; e += 256) s_g3[e] = g[e];
  if (tid < 50) {
    int k = tid >> 1, d = tid & 1;
    s_ms[k][d] = mu[tid];
    float sg = sig[tid];
    s_ms[k][2 + d] = 1.f / (sg * sg + 1e-15f);
  }
  if (tid < 16) s_r3[tid] = root[tid];
  __syncthreads();

  for (int e = tid; e < 1875; e += 256) {
    int s = e / 25, k = e % 25;
    float a = 0.f;
    #pragma unroll
    for (int i = 0; i < 16; ++i) a += s_x[s][i] * s_g3[i * 25 + k];
    s_xm[s][k] = a;
  }
  if (tid < 75) {
    int t = tid, c = 0;
    for (int s = 0; s < 75; ++s) {
      if (s == t) continue;
      float d0 = s_pos[t][0] - s_pos[s][0] + 1e-12f;
      float d1 = s_pos[t][1] - s_pos[s][1] + 1e-12f;
      c += (sqrtf(d0 * d0 + d1 * d1) < 0.5f) ? 1 : 0;
    }
    s_ideg[t] = 1.f / (float)(c < 1 ? 1 : c);
  }
  __syncthreads();

  for (int e = tid; e < 1875; e += 256) {
    int t = e / 25, k = e % 25;
    float mu0 = s_ms[k][0], mu1 = s_ms[k][1], iv0 = s_ms[k][2], iv1 = s_ms[k][3];
    float pt0 = s_pos[t][0], pt1 = s_pos[t][1];
    float a = 0.f;
    for (int s = 0; s < 75; ++s) {
      float d0 = pt0 - s_pos[s][0], d1 = pt1 - s_pos[s][1];
      float e0 = d0 + 1e-12f, e1 = d1 + 1e-12f;
      float dist = sqrtf(e0 * e0 + e1 * e1);
      bool m = (dist < 0.5f) && (s != t);
      float q0 = 2.f * d0 + 0.5f - mu0, q1 = 2.f * d1 + 0.5f - mu1;
      float ex = __expf(-0.5f * (q0 * q0 * iv0 + q1 * q1 * iv1));
      a += (m ? ex : 0.f) * s_xm[s][k];
    }
    s_part[t][k] = a;
  }
  __syncthreads();

  if (tid < 75) {
    int t = tid;
    float a = 0.f;
    #pragma unroll
    for (int k = 0; k < 25; ++k) a += s_part[t][k];
    float r = 0.f;
    #pragma unroll
    for (int i = 0; i < 16; ++i) r += s_x[t][i] * s_r3[i];
    xout[b * 75 + t] = tanhf(a * s_ideg[t] + r + bias[0]);
  }
}

// ---------------- MLP: [2+fdim] -> 128 -> 64 -> 2, elu everywhere ----------------
__global__ __launch_bounds__(256) void mlp_kernel(
    const float* __restrict__ pos_src, const float* __restrict__ feat,
    const float* __restrict__ w1, const float* __restrict__ b1,
    const float* __restrict__ w2, const float* __restrict__ b2,
    const float* __restrict__ w3, const float* __restrict__ b3,
    float* __restrict__ out, int rows, int fdim, int rep)
{
  const int tid = threadIdx.x, lane = tid & 63, wv = tid >> 6;
  const int din = fdim + 2;
  __shared__ float s_w1[34 * 128];
  __shared__ float s_w2[128 * 64];
  __shared__ float s_w3[64 * 2];
  __shared__ float s_b1[128];
  __shared__ float s_b2[64];
  __shared__ float s_b3[2];
  __shared__ float s_in[4][36];
  __shared__ float s_h1[4][128];

  for (int e = tid; e < din * 128; e += 256) s_w1[e] = w1[e];
  for (int e = tid; e < 8192; e += 256) s_w2[e] = w2[e];
  if (tid < 128) { s_w3[tid] = w3[tid]; s_b1[tid] = b1[tid]; }
  if (tid < 64) s_b2[tid] = b2[tid];
  if (tid < 2) s_b3[tid] = b3[tid];
  __syncthreads();

  for (int row = blockIdx.x * 4 + wv; row < rows; row += gridDim.x * 4) {
    if (lane < din)
      s_in[wv][lane] = (lane < 2) ? pos_src[(row / rep) * 2 + lane]
                                  : feat[row * fdim + lane - 2];
    // same-wave LDS ops are in-order; no cross-wave sharing of s_in/s_h1
    float a0 = s_b1[lane], a1 = s_b1[lane + 64];
    for (int i = 0; i < din; ++i) {
      float xv = s_in[wv][i];
      a0 += xv * s_w1[i * 128 + lane];
      a1 += xv * s_w1[i * 128 + lane + 64];
    }
    s_h1[wv][lane] = eluf(a0);
    s_h1[wv][lane + 64] = eluf(a1);
    float a2 = s_b2[lane];
    for (int i = 0; i < 128; ++i) a2 += s_h1[wv][i] * s_w2[i * 64 + lane];
    float h2 = eluf(a2);
    float c0 = h2 * s_w3[lane * 2];
    float c1 = h2 * s_w3[lane * 2 + 1];
    for (int off = 32; off; off >>= 1) {
      c0 += __shfl_down(c0, off);
      c1 += __shfl_down(c1, off);
    }
    if (lane == 0) {
      out[row * 2 + 0] = eluf(c0 + s_b3[0]);
      out[row * 2 + 1] = eluf(c1 + s_b3[1]);
    }
  }
}

extern "C" void kernel_launch(void* const* d_in, const int* in_sizes, int n_in,
                              void* d_out, int out_size, void* d_ws, size_t ws_size,
                              hipStream_t stream)
{
  const float* x     = (const float*)d_in[0];
  const float* pos   = (const float*)d_in[1];
  const float* g1    = (const float*)d_in[2];
  const float* mu1   = (const float*)d_in[3];
  const float* sig1  = (const float*)d_in[4];
  const float* root1 = (const float*)d_in[5];
  const float* cb1   = (const float*)d_in[6];
  const float* g2    = (const float*)d_in[7];
  const float* mu2   = (const float*)d_in[8];
  const float* sig2  = (const float*)d_in[9];
  const float* root2 = (const float*)d_in[10];
  const float* cb2   = (const float*)d_in[11];
  const float* g3    = (const float*)d_in[12];
  const float* mu3   = (const float*)d_in[13];
  const float* sig3  = (const float*)d_in[14];
  const float* root3 = (const float*)d_in[15];
  const float* cb3   = (const float*)d_in[16];
  const float* p1w1  = (const float*)d_in[17];
  const float* p1b1  = (const float*)d_in[18];
  const float* p1w2  = (const float*)d_in[19];
  const float* p1b2  = (const float*)d_in[20];
  const float* p1w3  = (const float*)d_in[21];
  const float* p1b3  = (const float*)d_in[22];
  const float* p2w1  = (const float*)d_in[23];
  const float* p2b1  = (const float*)d_in[24];
  const float* p2w2  = (const float*)d_in[25];
  const float* p2b2  = (const float*)d_in[26];
  const float* p2w3  = (const float*)d_in[27];
  const float* p2b3  = (const float*)d_in[28];

  float* out  = (float*)d_out;
  float* ws   = (float*)d_ws;
  float* x1   = ws;            // 5120*160   = 819200 floats
  float* pos1 = ws + 819200;   // 25600*2    = 51200
  float* x2   = ws + 870400;   // 76800*16   = 1228800
  float* x3   = out;           // 76800
  float* pos2 = out + 76800;   // 76800*2 = 153600

  conv1_kernel<<<dim3(1024), dim3(256), 0, stream>>>(x, pos, g1, mu1, sig1, root1, cb1, x1);
  mlp_kernel<<<dim3(1024), dim3(256), 0, stream>>>(pos, x1, p1w1, p1b1, p1w2, p1b2, p1w3, p1b3,
                                                   pos1, 25600, 32, 5);
  conv2_kernel<<<dim3(1024), dim3(256), 0, stream>>>(x1, pos1, g2, mu2, sig2, root2, cb2, x2);
  mlp_kernel<<<dim3(1024), dim3(256), 0, stream>>>(pos1, x2, p2w1, p2b1, p2w2, p2b2, p2w3, p2b3,
                                                   pos2, 76800, 16, 3);
  conv3_kernel<<<dim3(1024), dim3(256), 0, stream>>>(x2, pos2, g3, mu3, sig3, root3, cb3, x3);
}

// Round 2
// 419.245 us; speedup vs baseline: 1.3028x; 1.3028x over previous
//
#include <hip/hip_runtime.h>
#include <math.h>

// GaussianGenerator v2: per-graph fused GEMM+scatter convs (<=64KB LDS),
// table-driven conv3, block-GEMM MLPs. All fp32 (position path is mask-critical).

__device__ __forceinline__ float eluf(float v) { return v > 0.f ? v : __expf(v) - 1.f; }

#define NLOG2E_HALF (-0.72134752f)   // -0.5*log2(e)

// w slot mapping: k -> set*8+off, sets {0-4},{5-8},{9-12},{13-16},{17-20},{21-24}
__device__ __forceinline__ int kset_of(int k) { return k < 5 ? 0 : (1 + ((k - 5) >> 2)); }
__device__ __forceinline__ int koff_of(int k) { return k < 5 ? k : ((k - 5) & 3); }

// ---------------- conv1: n=5, fin=64, K=25, cout=160 ----------------
__global__ __launch_bounds__(512) void conv1_kernel(
    const float* __restrict__ x, const float* __restrict__ pos,
    const float* __restrict__ g, const float* __restrict__ mu, const float* __restrict__ sig,
    const float* __restrict__ root, const float* __restrict__ bias,
    float* __restrict__ xout)
{
  const int b = blockIdx.x, tid = threadIdx.x;
  __shared__ __align__(16) float s_xT[64][8];      // xT[i][r], r<5
  __shared__ __align__(16) float s_xmh[5][2080];   // xm half-buffer (k-half of 13)
  __shared__ __align__(16) float s_w[5][5][48];    // [s][t][slot] zero-padded
  __shared__ float s_pos[5][2];
  __shared__ float s_msc[25][4];                   // c0,c1,niv0,niv1
  __shared__ float s_ideg[5];
  __shared__ __align__(16) float s_red[3][5][160];

  // phase 0a: loads + zero w
  if (tid < 10) (&s_pos[0][0])[tid] = pos[b * 10 + tid];
  if (tid < 25) {
    float m0 = mu[2 * tid], m1 = mu[2 * tid + 1];
    float s0 = sig[2 * tid], s1 = sig[2 * tid + 1];
    s_msc[tid][0] = 0.5f - m0;
    s_msc[tid][1] = 0.5f - m1;
    s_msc[tid][2] = NLOG2E_HALF / (s0 * s0 + 1e-15f);
    s_msc[tid][3] = NLOG2E_HALF / (s1 * s1 + 1e-15f);
  }
  for (int e = tid; e < 320; e += 512) { int r = e >> 6, i = e & 63; s_xT[i][r] = x[(b * 5 + r) * 64 + i]; }
  for (int e = tid; e < 1200; e += 512) (&s_w[0][0][0])[e] = 0.f;
  __syncthreads();

  // phase 0b: gauss weights + degree
  for (int e = tid; e < 625; e += 512) {
    int s = e / 125, r = e % 125, t = r / 25, k = r % 25;
    float d0 = s_pos[t][0] - s_pos[s][0];
    float d1 = s_pos[t][1] - s_pos[s][1];
    float e0 = d0 + 1e-12f, e1 = d1 + 1e-12f;
    bool m = (e0 * e0 + e1 * e1 < 0.25f) && (s != t);
    float q0 = fmaf(2.f, d0, s_msc[k][0]);
    float q1 = fmaf(2.f, d1, s_msc[k][1]);
    float a = q0 * q0 * s_msc[k][2];
    a = fmaf(q1 * q1, s_msc[k][3], a);
    s_w[s][t][kset_of(k) * 8 + koff_of(k)] = m ? exp2f(a) : 0.f;
  }
  if (tid < 5) {
    int t = tid, c = 0;
    for (int s = 0; s < 5; ++s) {
      if (s == t) continue;
      float d0 = s_pos[t][0] - s_pos[s][0] + 1e-12f;
      float d1 = s_pos[t][1] - s_pos[s][1] + 1e-12f;
      c += (d0 * d0 + d1 * d1 < 0.25f) ? 1 : 0;
    }
    s_ideg[t] = 1.f / (float)(c < 1 ? 1 : c);
  }
  __syncthreads();

  float acc5[5] = {0.f, 0.f, 0.f, 0.f, 0.f};
  float racc[5] = {0.f, 0.f, 0.f, 0.f, 0.f};

  for (int h = 0; h < 2; ++h) {
    const int khalf0 = h * 13;
    const int ncols = h ? 1920 : 2080;
    const int ntasks = ncols >> 2;          // 4-col tiles, 5 rows each
    // GEMM: xmh[r][c] = sum_i x[r][i]*g[i][khalf0*160+c]
    for (int e = tid; e < ntasks; e += 512) {
      int c0 = e * 4;
      const float* gp = g + khalf0 * 160 + c0;
      float a0[5][4];
      #pragma unroll
      for (int r = 0; r < 5; ++r) { a0[r][0] = a0[r][1] = a0[r][2] = a0[r][3] = 0.f; }
      #pragma unroll 4
      for (int i = 0; i < 64; ++i) {
        float4 gv = *(const float4*)(gp + i * 4000);
        float4 xa = *(const float4*)&s_xT[i][0];
        float xe = s_xT[i][4];
        a0[0][0] = fmaf(xa.x, gv.x, a0[0][0]); a0[0][1] = fmaf(xa.x, gv.y, a0[0][1]);
        a0[0][2] = fmaf(xa.x, gv.z, a0[0][2]); a0[0][3] = fmaf(xa.x, gv.w, a0[0][3]);
        a0[1][0] = fmaf(xa.y, gv.x, a0[1][0]); a0[1][1] = fmaf(xa.y, gv.y, a0[1][1]);
        a0[1][2] = fmaf(xa.y, gv.z, a0[1][2]); a0[1][3] = fmaf(xa.y, gv.w, a0[1][3]);
        a0[2][0] = fmaf(xa.z, gv.x, a0[2][0]); a0[2][1] = fmaf(xa.z, gv.y, a0[2][1]);
        a0[2][2] = fmaf(xa.z, gv.z, a0[2][2]); a0[2][3] = fmaf(xa.z, gv.w, a0[2][3]);
        a0[3][0] = fmaf(xa.w, gv.x, a0[3][0]); a0[3][1] = fmaf(xa.w, gv.y, a0[3][1]);
        a0[3][2] = fmaf(xa.w, gv.z, a0[3][2]); a0[3][3] = fmaf(xa.w, gv.w, a0[3][3]);
        a0[4][0] = fmaf(xe, gv.x, a0[4][0]);   a0[4][1] = fmaf(xe, gv.y, a0[4][1]);
        a0[4][2] = fmaf(xe, gv.z, a0[4][2]);   a0[4][3] = fmaf(xe, gv.w, a0[4][3]);
      }
      #pragma unroll
      for (int r = 0; r < 5; ++r)
        *(float4*)&s_xmh[r][c0] = make_float4(a0[r][0], a0[r][1], a0[r][2], a0[r][3]);
    }
    __syncthreads();

    // scatter partial (k-partition) + root partial (half 0 only)
    if (tid < 480) {
      const int o = tid % 160, kp3 = tid / 160;
      const int kp = h * 3 + kp3;
      const int kbase = kp ? (5 + (kp - 1) * 4) : 0;
      const int ksize = kp ? 4 : 5;
      for (int s = 0; s < 5; ++s) {
        float xmc[8];
        #pragma unroll
        for (int sl = 0; sl < 8; ++sl) xmc[sl] = 0.f;
        for (int sl = 0; sl < ksize; ++sl)
          xmc[sl] = s_xmh[s][(kbase + sl - khalf0) * 160 + o];
        #pragma unroll
        for (int t = 0; t < 5; ++t) {
          const float* wp = &s_w[s][t][kp * 8];
          float4 w0 = *(const float4*)wp;
          float4 w1 = *(const float4*)(wp + 4);
          float a = w0.x * xmc[0] + w0.y * xmc[1] + w0.z * xmc[2] + w0.w * xmc[3];
          a += w1.x * xmc[4] + w1.y * xmc[5] + w1.z * xmc[6] + w1.w * xmc[7];
          acc5[t] += a;
        }
      }
      if (h == 0) {
        int i0 = kp3 * 21, i1 = (kp3 == 2) ? 64 : (i0 + 21);
        for (int i = i0; i < i1; ++i) {
          float rv = root[i * 160 + o];
          #pragma unroll
          for (int t = 0; t < 5; ++t) racc[t] = fmaf(s_xT[i][t], rv, racc[t]);
        }
      }
    }
    __syncthreads();
  }

  if (tid < 480) {
    const int o = tid % 160, kp3 = tid / 160;
    #pragma unroll
    for (int t = 0; t < 5; ++t)
      s_red[kp3][t][o] = acc5[t] * s_ideg[t] + racc[t];
  }
  __syncthreads();
  if (tid < 160) {
    int o = tid;
    #pragma unroll
    for (int t = 0; t < 5; ++t) {
      float v = s_red[0][t][o] + s_red[1][t][o] + s_red[2][t][o] + bias[o];
      xout[(b * 5 + t) * 160 + o] = eluf(v);
    }
  }
}

// ---------------- conv2: n=25, fin=32, K=25, cout=48 ----------------
__global__ __launch_bounds__(512) void conv2_kernel(
    const float* __restrict__ x, const float* __restrict__ pos,
    const float* __restrict__ g, const float* __restrict__ mu, const float* __restrict__ sig,
    const float* __restrict__ root, const float* __restrict__ bias,
    float* __restrict__ xout)
{
  const int b = blockIdx.x, tid = threadIdx.x;
  __shared__ __align__(16) char smem[58304];
  float* s_xT  = (float*)smem;                    // [32][28]        3584B
  float* s_xmk = (float*)(smem + 3584);           // [25][340]       34000B
  float* s_wk  = (float*)(smem + 37584);          // [25][25][8]     20000B (aliased by red)
  float* s_red = s_wk;                            // [2][25][48]     9600B
  float* s_pos = (float*)(smem + 57584);          // 50f
  float* s_msc = (float*)(smem + 57792);          // [25][4]
  float* s_ideg= (float*)(smem + 58192);          // 25f

  if (tid < 50) s_pos[tid] = pos[b * 50 + tid];
  if (tid < 25) {
    float m0 = mu[2 * tid], m1 = mu[2 * tid + 1];
    float s0 = sig[2 * tid], s1 = sig[2 * tid + 1];
    s_msc[tid * 4 + 0] = 0.5f - m0;
    s_msc[tid * 4 + 1] = 0.5f - m1;
    s_msc[tid * 4 + 2] = NLOG2E_HALF / (s0 * s0 + 1e-15f);
    s_msc[tid * 4 + 3] = NLOG2E_HALF / (s1 * s1 + 1e-15f);
  }
  for (int e = tid; e < 800; e += 512) { int r = e >> 5, i = e & 31; s_xT[i * 28 + r] = x[(b * 25 + r) * 32 + i]; }
  __syncthreads();
  if (tid < 25) {
    int t = tid, c = 0;
    for (int s = 0; s < 25; ++s) {
      if (s == t) continue;
      float d0 = s_pos[t * 2] - s_pos[s * 2] + 1e-12f;
      float d1 = s_pos[t * 2 + 1] - s_pos[s * 2 + 1] + 1e-12f;
      c += (d0 * d0 + d1 * d1 < 0.25f) ? 1 : 0;
    }
    s_ideg[t] = 1.f / (float)(c < 1 ? 1 : c);
  }

  const int o48 = tid % 48, tb = (tid / 48) % 5, sp = tid / 240;  // scatter role (tid<480)
  float acc5[5] = {0.f, 0.f, 0.f, 0.f, 0.f};

  const int kc_arr0[4] = {7, 6, 6, 6};
  const int k0_arr[4]  = {0, 7, 13, 19};

  for (int ch = 0; ch < 4; ++ch) {
    const int kc = kc_arr0[ch], k0 = k0_arr[ch];
    __syncthreads();   // protect previous chunk's wk/xmk reads
    // gauss weights for this k-chunk: wk[s][t][slot8]
    for (int e = tid; e < 5000; e += 512) {
      int s = e / 200, r = e % 200, t = r >> 3, kk = r & 7;
      float wv = 0.f;
      if (kk < kc) {
        int k = k0 + kk;
        float d0 = s_pos[t * 2]     - s_pos[s * 2];
        float d1 = s_pos[t * 2 + 1] - s_pos[s * 2 + 1];
        float e0 = d0 + 1e-12f, e1 = d1 + 1e-12f;
        bool m = (e0 * e0 + e1 * e1 < 0.25f) && (s != t);
        float q0 = fmaf(2.f, d0, s_msc[k * 4 + 0]);
        float q1 = fmaf(2.f, d1, s_msc[k * 4 + 1]);
        float a = q0 * q0 * s_msc[k * 4 + 2];
        a = fmaf(q1 * q1, s_msc[k * 4 + 3], a);
        wv = m ? exp2f(a) : 0.f;
      }
      s_wk[e] = wv;
    }
    // GEMM chunk: xmk[r][kk*48+o] = sum_i x[r][i]*g2[i][ (k0+kk)*48+o ]
    const int ncol4 = (kc * 48) >> 2;
    const int ntask = 5 * ncol4;
    if (tid < ntask) {
      int rb = tid / ncol4, cb = tid % ncol4;
      int r0 = rb * 5, c0 = cb * 4;
      const float* gp = g + k0 * 48 + c0;
      float a0[5][4];
      #pragma unroll
      for (int r = 0; r < 5; ++r) { a0[r][0] = a0[r][1] = a0[r][2] = a0[r][3] = 0.f; }
      #pragma unroll 4
      for (int i = 0; i < 32; ++i) {
        float4 gv = *(const float4*)(gp + i * 1200);
        #pragma unroll
        for (int r = 0; r < 5; ++r) {
          float xv = s_xT[i * 28 + r0 + r];
          a0[r][0] = fmaf(xv, gv.x, a0[r][0]); a0[r][1] = fmaf(xv, gv.y, a0[r][1]);
          a0[r][2] = fmaf(xv, gv.z, a0[r][2]); a0[r][3] = fmaf(xv, gv.w, a0[r][3]);
        }
      }
      #pragma unroll
      for (int r = 0; r < 5; ++r)
        *(float4*)&s_xmk[(r0 + r) * 340 + c0] = make_float4(a0[r][0], a0[r][1], a0[r][2], a0[r][3]);
    }
    __syncthreads();
    // scatter accumulation (acc5 persists in regs across chunks)
    if (tid < 480) {
      for (int s = sp; s < 25; s += 2) {
        float xmc[8];
        #pragma unroll
        for (int sl = 0; sl < 8; ++sl) xmc[sl] = 0.f;
        for (int sl = 0; sl < kc; ++sl) xmc[sl] = s_xmk[s * 340 + sl * 48 + o48];
        #pragma unroll
        for (int tt = 0; tt < 5; ++tt) {
          const float* wp = &s_wk[(s * 25 + tb * 5 + tt) * 8];
          float4 w0 = *(const float4*)wp;
          float4 w1 = *(const float4*)(wp + 4);
          float a = w0.x * xmc[0] + w0.y * xmc[1] + w0.z * xmc[2] + w0.w * xmc[3];
          a += w1.x * xmc[4] + w1.y * xmc[5] + w1.z * xmc[6] + w1.w * xmc[7];
          acc5[tt] += a;
        }
      }
    }
  }
  __syncthreads();   // done with wk -> alias as red
  if (tid < 480) {
    #pragma unroll
    for (int tt = 0; tt < 5; ++tt)
      s_red[(sp * 25 + tb * 5 + tt) * 48 + o48] = acc5[tt];
  }
  __syncthreads();
  for (int e = tid; e < 1200; e += 512) {
    int t = e / 48, o = e % 48;
    float v = (s_red[t * 48 + o] + s_red[(25 + t) * 48 + o]) * s_ideg[t];
    for (int i = 0; i < 32; ++i)
      v = fmaf(s_xT[i * 28 + t], root[i * 48 + o], v);
    xout[(b * 25 + t) * 48 + o] = eluf(v + bias[o]);
  }
}

// ---------------- conv3: n=75, fin=16, K=25, cout=1, tanh ----------------
__global__ __launch_bounds__(256) void conv3_kernel(
    const float* __restrict__ x, const float* __restrict__ pos,
    const float* __restrict__ g, const float* __restrict__ mu, const float* __restrict__ sig,
    const float* __restrict__ root, const float* __restrict__ bias,
    float* __restrict__ xout)
{
  const int b = blockIdx.x, tid = threadIdx.x;
  __shared__ float s_pos[75][2];
  __shared__ float s_x[75][16];
  __shared__ float s_g3[400];
  __shared__ float s_msc[25][4];
  __shared__ float s_ideg[75];
  __shared__ float s_xm[75][25];
  __shared__ __align__(8) float s_u[75][75][2];   // masked doubled diffs (1e30 sentinel)
  __shared__ float s_out[75];
  __shared__ float s_r3[16];

  if (tid < 150) (&s_pos[0][0])[tid] = pos[b * 150 + tid];
  for (int e = tid; e < 1200; e += 256) (&s_x[0][0])[e] = x[b * 1200 + e];
  for (int e = tid; e < 400; e += 256) s_g3[e] = g[e];
  if (tid < 25) {
    float m0 = mu[2 * tid], m1 = mu[2 * tid + 1];
    float s0 = sig[2 * tid], s1 = sig[2 * tid + 1];
    s_msc[tid][0] = 0.5f - m0;
    s_msc[tid][1] = 0.5f - m1;
    s_msc[tid][2] = NLOG2E_HALF / (s0 * s0 + 1e-15f);
    s_msc[tid][3] = NLOG2E_HALF / (s1 * s1 + 1e-15f);
  }
  if (tid < 16) s_r3[tid] = root[tid];
  if (tid < 75) s_out[tid] = 0.f;
  __syncthreads();

  for (int e = tid; e < 1875; e += 256) {
    int s = e / 25, k = e % 25;
    float a = 0.f;
    #pragma unroll
    for (int i = 0; i < 16; ++i) a = fmaf(s_x[s][i], s_g3[i * 25 + k], a);
    s_xm[s][k] = a;
  }
  for (int e = tid; e < 5625; e += 256) {
    int t = e / 75, s = e % 75;
    float d0 = s_pos[t][0] - s_pos[s][0];
    float d1 = s_pos[t][1] - s_pos[s][1];
    float e0 = d0 + 1e-12f, e1 = d1 + 1e-12f;
    bool m = (e0 * e0 + e1 * e1 < 0.25f) && (s != t);
    s_u[t][s][0] = m ? 2.f * d0 : 1e30f;
    s_u[t][s][1] = m ? 2.f * d1 : 0.f;
  }
  if (tid < 75) {
    int t = tid, c = 0;
    for (int s = 0; s < 75; ++s) {
      if (s == t) continue;
      float d0 = s_pos[t][0] - s_pos[s][0] + 1e-12f;
      float d1 = s_pos[t][1] - s_pos[s][1] + 1e-12f;
      c += (d0 * d0 + d1 * d1 < 0.25f) ? 1 : 0;
    }
    s_ideg[t] = 1.f / (float)(c < 1 ? 1 : c);
  }
  __syncthreads();

  for (int e = tid; e < 1875; e += 256) {
    int t = e / 25, k = e % 25;
    float c0 = s_msc[k][0], c1 = s_msc[k][1], n0 = s_msc[k][2], n1 = s_msc[k][3];
    const float2* up = (const float2*)&s_u[t][0][0];
    float a = 0.f;
    for (int s = 0; s < 75; ++s) {
      float2 uv = up[s];
      float q0 = uv.x + c0, q1 = uv.y + c1;
      float ar = q0 * q0 * n0;
      ar = fmaf(q1 * q1, n1, ar);
      a = fmaf(exp2f(ar), s_xm[s][k], a);
    }
    atomicAdd(&s_out[t], a);
  }
  __syncthreads();

  if (tid < 75) {
    int t = tid;
    float r = 0.f;
    #pragma unroll
    for (int i = 0; i < 16; ++i) r = fmaf(s_x[t][i], s_r3[i], r);
    xout[b * 75 + t] = tanhf(s_out[t] * s_ideg[t] + r + bias[0]);
  }
}

// ---------------- MLP: [2+fdim] -> 128 -> 64 -> 2, elu everywhere ----------------
// 64 rows per block; transposed LDS activations; weights streamed from global (L1/L2).
__global__ __launch_bounds__(256) void mlp_kernel(
    const float* __restrict__ pos_src, const float* __restrict__ feat,
    const float* __restrict__ w1, const float* __restrict__ b1,
    const float* __restrict__ w2, const float* __restrict__ b2,
    const float* __restrict__ w3, const float* __restrict__ b3,
    float* __restrict__ out, int fdim, int rep)
{
  const int tid = threadIdx.x;
  const int row0 = blockIdx.x * 64;
  const int din = fdim + 2;
  __shared__ __align__(16) float s_inT[34][68];
  __shared__ __align__(16) float s_h1T[128][68];
  __shared__ __align__(16) float s_h2T[64][68];

  if (tid < 128) {
    int r = tid >> 1, d = tid & 1;
    s_inT[d][r] = pos_src[((row0 + r) / rep) * 2 + d];
  }
  for (int e = tid; e < 64 * fdim; e += 256) {
    int r = e / fdim, c = e % fdim;
    s_inT[2 + c][r] = feat[(row0 + r) * fdim + c];
  }
  __syncthreads();

  // layer 1: 64x128, tiles 4r x 8j
  {
    const int rb = tid >> 4, jb = tid & 15;
    const int r0 = rb << 2, j0 = jb << 3;
    float acc[4][8];
    #pragma unroll
    for (int jj = 0; jj < 8; ++jj) {
      float bv = b1[j0 + jj];
      acc[0][jj] = bv; acc[1][jj] = bv; acc[2][jj] = bv; acc[3][jj] = bv;
    }
    for (int i = 0; i < din; ++i) {
      float4 xa = *(const float4*)&s_inT[i][r0];
      float4 wa = *(const float4*)(w1 + i * 128 + j0);
      float4 wb = *(const float4*)(w1 + i * 128 + j0 + 4);
      float wv[8] = {wa.x, wa.y, wa.z, wa.w, wb.x, wb.y, wb.z, wb.w};
      #pragma unroll
      for (int jj = 0; jj < 8; ++jj) {
        acc[0][jj] = fmaf(xa.x, wv[jj], acc[0][jj]);
        acc[1][jj] = fmaf(xa.y, wv[jj], acc[1][jj]);
        acc[2][jj] = fmaf(xa.z, wv[jj], acc[2][jj]);
        acc[3][jj] = fmaf(xa.w, wv[jj], acc[3][jj]);
      }
    }
    #pragma unroll
    for (int jj = 0; jj < 8; ++jj)
      *(float4*)&s_h1T[j0 + jj][r0] =
        make_float4(eluf(acc[0][jj]), eluf(acc[1][jj]), eluf(acc[2][jj]), eluf(acc[3][jj]));
  }
  __syncthreads();

  // layer 2: 64x64, tiles 4r x 4j
  {
    const int rb = tid >> 4, jb = tid & 15;
    const int r0 = rb << 2, j0 = jb << 2;
    float acc[4][4];
    #pragma unroll
    for (int jj = 0; jj < 4; ++jj) {
      float bv = b2[j0 + jj];
      acc[0][jj] = bv; acc[1][jj] = bv; acc[2][jj] = bv; acc[3][jj] = bv;
    }
    #pragma unroll 4
    for (int i = 0; i < 128; ++i) {
      float4 ha = *(const float4*)&s_h1T[i][r0];
      float4 wa = *(const float4*)(w2 + i * 64 + j0);
      float wv[4] = {wa.x, wa.y, wa.z, wa.w};
      #pragma unroll
      for (int jj = 0; jj < 4; ++jj) {
        acc[0][jj] = fmaf(ha.x, wv[jj], acc[0][jj]);
        acc[1][jj] = fmaf(ha.y, wv[jj], acc[1][jj]);
        acc[2][jj] = fmaf(ha.z, wv[jj], acc[2][jj]);
        acc[3][jj] = fmaf(ha.w, wv[jj], acc[3][jj]);
      }
    }
    #pragma unroll
    for (int jj = 0; jj < 4; ++jj)
      *(float4*)&s_h2T[j0 + jj][r0] =
        make_float4(eluf(acc[0][jj]), eluf(acc[1][jj]), eluf(acc[2][jj]), eluf(acc[3][jj]));
  }
  __syncthreads();

  // layer 3: 64x2
  if (tid < 128) {
    int r = tid >> 1, c = tid & 1;
    float a = b3[c];
    #pragma unroll 8
    for (int j = 0; j < 64; ++j)
      a = fmaf(s_h2T[j][r], w3[j * 2 + c], a);
    out[(row0 + r) * 2 + c] = eluf(a);
  }
}

extern "C" void kernel_launch(void* const* d_in, const int* in_sizes, int n_in,
                              void* d_out, int out_size, void* d_ws, size_t ws_size,
                              hipStream_t stream)
{
  const float* x     = (const float*)d_in[0];
  const float* pos   = (const float*)d_in[1];
  const float* g1    = (const float*)d_in[2];
  const float* mu1   = (const float*)d_in[3];
  const float* sig1  = (const float*)d_in[4];
  const float* root1 = (const float*)d_in[5];
  const float* cb1   = (const float*)d_in[6];
  const float* g2    = (const float*)d_in[7];
  const float* mu2   = (const float*)d_in[8];
  const float* sig2  = (const float*)d_in[9];
  const float* root2 = (const float*)d_in[10];
  const float* cb2   = (const float*)d_in[11];
  const float* g3    = (const float*)d_in[12];
  const float* mu3   = (const float*)d_in[13];
  const float* sig3  = (const float*)d_in[14];
  const float* root3 = (const float*)d_in[15];
  const float* cb3   = (const float*)d_in[16];
  const float* p1w1  = (const float*)d_in[17];
  const float* p1b1  = (const float*)d_in[18];
  const float* p1w2  = (const float*)d_in[19];
  const float* p1b2  = (const float*)d_in[20];
  const float* p1w3  = (const float*)d_in[21];
  const float* p1b3  = (const float*)d_in[22];
  const float* p2w1  = (const float*)d_in[23];
  const float* p2b1  = (const float*)d_in[24];
  const float* p2w2  = (const float*)d_in[25];
  const float* p2b2  = (const float*)d_in[26];
  const float* p2w3  = (const float*)d_in[27];
  const float* p2b3  = (const float*)d_in[28];

  float* out  = (float*)d_out;
  float* ws   = (float*)d_ws;
  float* x1   = ws;            // 5120*160 = 819200 floats
  float* pos1 = ws + 819200;   // 25600*2  = 51200
  float* x2   = ws + 870400;   // 76800*16 = 1228800
  float* x3   = out;           // 76800
  float* pos2 = out + 76800;   // 76800*2

  conv1_kernel<<<dim3(1024), dim3(512), 0, stream>>>(x, pos, g1, mu1, sig1, root1, cb1, x1);
  mlp_kernel<<<dim3(400), dim3(256), 0, stream>>>(pos, x1, p1w1, p1b1, p1w2, p1b2, p1w3, p1b3,
                                                  pos1, 32, 5);
  conv2_kernel<<<dim3(1024), dim3(512), 0, stream>>>(x1, pos1, g2, mu2, sig2, root2, cb2, x2);
  mlp_kernel<<<dim3(1200), dim3(256), 0, stream>>>(pos1, x2, p2w1, p2b1, p2w2, p2b2, p2w3, p2b3,
                                                  pos2, 16, 3);
  conv3_kernel<<<dim3(1024), dim3(256), 0, stream>>>(x2, pos2, g3, mu3, sig3, root3, cb3, x3);
}

// Round 3
// 353.320 us; speedup vs baseline: 1.5459x; 1.1866x over previous
//
#include <hip/hip_runtime.h>
#include <math.h>

// GaussianGenerator v3: scatter-as-GEMM convs with transposed W tables,
// 2-graphs/block conv1 (halves g1 L2 traffic), 5k-amortized conv3.
// All fp32 (pos chain is mask-critical; no bf16 anywhere upstream of masks).

__device__ __forceinline__ float eluf(float v) { return v > 0.f ? v : __expf(v) - 1.f; }

#define NLOG2E_HALF (-0.72134752f)   // -0.5*log2(e)

// ---------------- conv1: n=5, fin=64, K=25, cout=160; 2 graphs/block ----------------
__global__ __launch_bounds__(512) void conv1_kernel(
    const float* __restrict__ x, const float* __restrict__ pos,
    const float* __restrict__ g, const float* __restrict__ mu, const float* __restrict__ sig,
    const float* __restrict__ root, const float* __restrict__ bias,
    float* __restrict__ xout)
{
  const int b = blockIdx.x, tid = threadIdx.x;
  __shared__ __align__(16) float s_xT[64 * 12];          // [i][r], r=g*5+s (10, pad 12)
  __shared__ __align__(16) float s_xm[10 * 832];         // chunk GEMM out [r][<=800]; cols 800..831 zero
  __shared__ __align__(16) float s_w[2 * 5 * 5 * 28];    // [g][t][ch][28] (slots 25..27 zero)
  __shared__ __align__(16) float s_red[2 * 2 * 5 * 160]; // [ks][g][t][o]
  __shared__ float s_pos[20];
  __shared__ float s_msc[25][4];
  __shared__ float s_ideg[10];

  if (tid < 20) s_pos[tid] = pos[b * 20 + tid];
  if (tid < 25) {
    float m0 = mu[2 * tid], m1 = mu[2 * tid + 1];
    float s0 = sig[2 * tid], s1 = sig[2 * tid + 1];
    s_msc[tid][0] = 0.5f - m0;
    s_msc[tid][1] = 0.5f - m1;
    s_msc[tid][2] = NLOG2E_HALF / (s0 * s0 + 1e-15f);
    s_msc[tid][3] = NLOG2E_HALF / (s1 * s1 + 1e-15f);
  }
  for (int e = tid; e < 640; e += 512) { int nd = e >> 6, i = e & 63; s_xT[i * 12 + nd] = x[b * 640 + nd * 64 + i]; }
  for (int e = tid; e < 320; e += 512) { int r = e / 32, c = e % 32; s_xm[r * 832 + 800 + c] = 0.f; }
  __syncthreads();

  if (tid < 10) {
    int gg = tid / 5, t = tid % 5, c = 0;
    for (int s = 0; s < 5; ++s) {
      if (s == t) continue;
      float d0 = s_pos[(gg * 5 + t) * 2]     - s_pos[(gg * 5 + s) * 2]     + 1e-12f;
      float d1 = s_pos[(gg * 5 + t) * 2 + 1] - s_pos[(gg * 5 + s) * 2 + 1] + 1e-12f;
      c += (d0 * d0 + d1 * d1 < 0.25f) ? 1 : 0;
    }
    s_ideg[tid] = 1.f / (float)(c < 1 ? 1 : c);
  }
  // W[g][t][ch][skl], skl = kk*5+s (k = ch*5+kk), zero-padded 25..27
  for (int e = tid; e < 1400; e += 512) {
    int gg = e / 700, r2 = e % 700, t = r2 / 140, c = r2 % 140;
    int ch = c / 28, skl = c % 28;
    float wv = 0.f;
    if (skl < 25) {
      int kk = skl / 5, s = skl % 5, k = ch * 5 + kk;
      float d0 = s_pos[(gg * 5 + t) * 2]     - s_pos[(gg * 5 + s) * 2];
      float d1 = s_pos[(gg * 5 + t) * 2 + 1] - s_pos[(gg * 5 + s) * 2 + 1];
      float e0 = d0 + 1e-12f, e1 = d1 + 1e-12f;
      bool m = (e0 * e0 + e1 * e1 < 0.25f) && (s != t);
      float q0 = fmaf(2.f, d0, s_msc[k][0]);
      float q1 = fmaf(2.f, d1, s_msc[k][1]);
      float a = q0 * q0 * s_msc[k][2];
      a = fmaf(q1 * q1, s_msc[k][3], a);
      wv = m ? exp2f(a) : 0.f;
    }
    s_w[e] = wv;
  }
  __syncthreads();

  float sacc[5][2];
  #pragma unroll
  for (int t = 0; t < 5; ++t) { sacc[t][0] = 0.f; sacc[t][1] = 0.f; }
  const int sg = tid / 160, sr = tid % 160, sks = sr / 80, sob = sr % 80;
  const int so0 = sob * 2;

  for (int ch = 0; ch < 5; ++ch) {
    // GEMM: 10r x 2c tiles over 800 cols (5k x 160o), K=64
    if (tid < 400) {
      const int c0 = tid * 2;
      const float* gp = g + ch * 800 + c0;
      float a[10][2];
      #pragma unroll
      for (int r = 0; r < 10; ++r) { a[r][0] = 0.f; a[r][1] = 0.f; }
      #pragma unroll 4
      for (int i = 0; i < 64; ++i) {
        float2 gv = *(const float2*)(gp + i * 4000);
        float4 xa = *(const float4*)&s_xT[i * 12];
        float4 xb = *(const float4*)&s_xT[i * 12 + 4];
        float2 xc = *(const float2*)&s_xT[i * 12 + 8];
        a[0][0] = fmaf(xa.x, gv.x, a[0][0]); a[0][1] = fmaf(xa.x, gv.y, a[0][1]);
        a[1][0] = fmaf(xa.y, gv.x, a[1][0]); a[1][1] = fmaf(xa.y, gv.y, a[1][1]);
        a[2][0] = fmaf(xa.z, gv.x, a[2][0]); a[2][1] = fmaf(xa.z, gv.y, a[2][1]);
        a[3][0] = fmaf(xa.w, gv.x, a[3][0]); a[3][1] = fmaf(xa.w, gv.y, a[3][1]);
        a[4][0] = fmaf(xb.x, gv.x, a[4][0]); a[4][1] = fmaf(xb.x, gv.y, a[4][1]);
        a[5][0] = fmaf(xb.y, gv.x, a[5][0]); a[5][1] = fmaf(xb.y, gv.y, a[5][1]);
        a[6][0] = fmaf(xb.z, gv.x, a[6][0]); a[6][1] = fmaf(xb.z, gv.y, a[6][1]);
        a[7][0] = fmaf(xb.w, gv.x, a[7][0]); a[7][1] = fmaf(xb.w, gv.y, a[7][1]);
        a[8][0] = fmaf(xc.x, gv.x, a[8][0]); a[8][1] = fmaf(xc.x, gv.y, a[8][1]);
        a[9][0] = fmaf(xc.y, gv.x, a[9][0]); a[9][1] = fmaf(xc.y, gv.y, a[9][1]);
      }
      #pragma unroll
      for (int r = 0; r < 10; ++r)
        *(float2*)&s_xm[r * 832 + c0] = make_float2(a[r][0], a[r][1]);
    }
    __syncthreads();
    // scatter: tile 5t x 2o, K-split 2 (slice 16 / 12+pad); compile-time sk decode
    if (tid < 320) {
#define C1_STEP(SK0) { \
      float2 m0 = *(const float2*)&s_xm[(sg * 5 + ((SK0) % 5)) * 832 + ((SK0) / 5) * 160 + so0]; \
      float2 m1 = *(const float2*)&s_xm[(sg * 5 + (((SK0) + 1) % 5)) * 832 + (((SK0) + 1) / 5) * 160 + so0]; \
      float2 m2 = *(const float2*)&s_xm[(sg * 5 + (((SK0) + 2) % 5)) * 832 + (((SK0) + 2) / 5) * 160 + so0]; \
      float2 m3 = *(const float2*)&s_xm[(sg * 5 + (((SK0) + 3) % 5)) * 832 + (((SK0) + 3) / 5) * 160 + so0]; \
      _Pragma("unroll") \
      for (int t = 0; t < 5; ++t) { \
        const float4 wv = *(const float4*)&s_w[((sg * 5 + t) * 5 + ch) * 28 + (SK0)]; \
        sacc[t][0] = fmaf(wv.x, m0.x, sacc[t][0]); sacc[t][1] = fmaf(wv.x, m0.y, sacc[t][1]); \
        sacc[t][0] = fmaf(wv.y, m1.x, sacc[t][0]); sacc[t][1] = fmaf(wv.y, m1.y, sacc[t][1]); \
        sacc[t][0] = fmaf(wv.z, m2.x, sacc[t][0]); sacc[t][1] = fmaf(wv.z, m2.y, sacc[t][1]); \
        sacc[t][0] = fmaf(wv.w, m3.x, sacc[t][0]); sacc[t][1] = fmaf(wv.w, m3.y, sacc[t][1]); \
      } }
      if (sks == 0) { C1_STEP(0) C1_STEP(4) C1_STEP(8) C1_STEP(12) }
      else          { C1_STEP(16) C1_STEP(20) C1_STEP(24) }
#undef C1_STEP
    }
    __syncthreads();
  }

  // root chunk: XM_root[r][o<160] = x @ root (tile 2r x 2c)
  if (tid < 400) {
    const int rb = tid / 80, cb = tid % 80;
    const int r0 = rb * 2, c0 = cb * 2;
    float a00 = 0.f, a01 = 0.f, a10 = 0.f, a11 = 0.f;
    #pragma unroll 4
    for (int i = 0; i < 64; ++i) {
      float2 rv = *(const float2*)(root + i * 160 + c0);
      float2 xv = *(const float2*)&s_xT[i * 12 + r0];
      a00 = fmaf(xv.x, rv.x, a00); a01 = fmaf(xv.x, rv.y, a01);
      a10 = fmaf(xv.y, rv.x, a10); a11 = fmaf(xv.y, rv.y, a11);
    }
    *(float2*)&s_xm[r0 * 832 + c0]       = make_float2(a00, a01);
    *(float2*)&s_xm[(r0 + 1) * 832 + c0] = make_float2(a10, a11);
  }
  if (tid < 320) {
    #pragma unroll
    for (int t = 0; t < 5; ++t) {
      s_red[((sks * 2 + sg) * 5 + t) * 160 + so0]     = sacc[t][0];
      s_red[((sks * 2 + sg) * 5 + t) * 160 + so0 + 1] = sacc[t][1];
    }
  }
  __syncthreads();
  for (int e = tid; e < 1600; e += 512) {
    int gg = e / 800, r2 = e % 800, t = r2 / 160, o = r2 % 160;
    float v = s_red[(gg * 5 + t) * 160 + o] + s_red[((2 + gg) * 5 + t) * 160 + o];
    v = v * s_ideg[gg * 5 + t] + s_xm[(gg * 5 + t) * 832 + o] + bias[o];
    xout[b * 1600 + e] = eluf(v);
  }
}

// ---------------- conv2: n=25, fin=32, K=25, cout=48 ----------------
__global__ __launch_bounds__(320) void conv2_kernel(
    const float* __restrict__ x, const float* __restrict__ pos,
    const float* __restrict__ g, const float* __restrict__ mu, const float* __restrict__ sig,
    const float* __restrict__ root, const float* __restrict__ bias,
    float* __restrict__ xout)
{
  const int b = blockIdx.x, tid = threadIdx.x;
  __shared__ __align__(16) float s_xT[32 * 28];   // [i][r], r<25 pad 28
  __shared__ __align__(16) float s_xm[128 * 52];  // [sk=kk*25+s][o<48 pad 52]; rows 125..127 zero. aliased as red at end
  __shared__ __align__(16) float s_w[25 * 128];   // [t][sk], cols 125..127 zero
  __shared__ float s_pos[50];
  __shared__ float s_msc[25][4];
  __shared__ float s_ideg[25];

  if (tid < 50) s_pos[tid] = pos[b * 50 + tid];
  if (tid < 25) {
    float m0 = mu[2 * tid], m1 = mu[2 * tid + 1];
    float s0 = sig[2 * tid], s1 = sig[2 * tid + 1];
    s_msc[tid][0] = 0.5f - m0;
    s_msc[tid][1] = 0.5f - m1;
    s_msc[tid][2] = NLOG2E_HALF / (s0 * s0 + 1e-15f);
    s_msc[tid][3] = NLOG2E_HALF / (s1 * s1 + 1e-15f);
  }
  for (int e = tid; e < 800; e += 320) { int r = e / 32, i = e % 32; s_xT[i * 28 + r] = x[b * 800 + e]; }
  for (int e = tid; e < 156; e += 320) { s_xm[(125 + e / 52) * 52 + e % 52] = 0.f; }
  __syncthreads();
  if (tid < 25) {
    int t = tid, c = 0;
    for (int s = 0; s < 25; ++s) {
      if (s == t) continue;
      float d0 = s_pos[t * 2]     - s_pos[s * 2]     + 1e-12f;
      float d1 = s_pos[t * 2 + 1] - s_pos[s * 2 + 1] + 1e-12f;
      c += (d0 * d0 + d1 * d1 < 0.25f) ? 1 : 0;
    }
    s_ideg[t] = 1.f / (float)(c < 1 ? 1 : c);
  }
  __syncthreads();

  const int sks = tid / 60, srr = tid % 60, stb = srr / 12, sob = srr % 12;
  const int t0 = stb * 5, o0 = sob * 4, kbase = sks * 32;
  float acc[5][4];
  #pragma unroll
  for (int tt = 0; tt < 5; ++tt) { acc[tt][0] = acc[tt][1] = acc[tt][2] = acc[tt][3] = 0.f; }

  for (int ch = 0; ch < 5; ++ch) {
    // wgen: W[t][kk*25+s] for k = ch*5+kk; zero cols 125..127
    for (int e = tid; e < 3200; e += 320) {
      int t = e >> 7, c = e & 127;
      float wv = 0.f;
      if (c < 125) {
        int kk = c / 25, s = c % 25, k = ch * 5 + kk;
        float d0 = s_pos[t * 2]     - s_pos[s * 2];
        float d1 = s_pos[t * 2 + 1] - s_pos[s * 2 + 1];
        float e0 = d0 + 1e-12f, e1 = d1 + 1e-12f;
        bool m = (e0 * e0 + e1 * e1 < 0.25f) && (s != t);
        float q0 = fmaf(2.f, d0, s_msc[k][0]);
        float q1 = fmaf(2.f, d1, s_msc[k][1]);
        float a = q0 * q0 * s_msc[k][2];
        a = fmaf(q1 * q1, s_msc[k][3], a);
        wv = m ? exp2f(a) : 0.f;
      }
      s_w[e] = wv;
    }
    // GEMM: xm rows kk*25+s, cols o; tile 5s x 4c over 25s x 240c, K=32
    if (tid < 300) {
      const int rb = tid / 60, cb = tid % 60;
      const int s0 = rb * 5, c0 = cb * 4;
      const int kk = c0 / 48, og = c0 % 48;
      const float* gp = g + ch * 240 + c0;
      float a[5][4];
      #pragma unroll
      for (int r = 0; r < 5; ++r) { a[r][0] = a[r][1] = a[r][2] = a[r][3] = 0.f; }
      #pragma unroll 4
      for (int i = 0; i < 32; ++i) {
        float4 gv = *(const float4*)(gp + i * 1200);
        float x0 = s_xT[i * 28 + s0];
        float x1 = s_xT[i * 28 + s0 + 1];
        float x2 = s_xT[i * 28 + s0 + 2];
        float x3 = s_xT[i * 28 + s0 + 3];
        float x4 = s_xT[i * 28 + s0 + 4];
        a[0][0] = fmaf(x0, gv.x, a[0][0]); a[0][1] = fmaf(x0, gv.y, a[0][1]);
        a[0][2] = fmaf(x0, gv.z, a[0][2]); a[0][3] = fmaf(x0, gv.w, a[0][3]);
        a[1][0] = fmaf(x1, gv.x, a[1][0]); a[1][1] = fmaf(x1, gv.y, a[1][1]);
        a[1][2] = fmaf(x1, gv.z, a[1][2]); a[1][3] = fmaf(x1, gv.w, a[1][3]);
        a[2][0] = fmaf(x2, gv.x, a[2][0]); a[2][1] = fmaf(x2, gv.y, a[2][1]);
        a[2][2] = fmaf(x2, gv.z, a[2][2]); a[2][3] = fmaf(x2, gv.w, a[2][3]);
        a[3][0] = fmaf(x3, gv.x, a[3][0]); a[3][1] = fmaf(x3, gv.y, a[3][1]);
        a[3][2] = fmaf(x3, gv.z, a[3][2]); a[3][3] = fmaf(x3, gv.w, a[3][3]);
        a[4][0] = fmaf(x4, gv.x, a[4][0]); a[4][1] = fmaf(x4, gv.y, a[4][1]);
        a[4][2] = fmaf(x4, gv.z, a[4][2]); a[4][3] = fmaf(x4, gv.w, a[4][3]);
      }
      #pragma unroll
      for (int j = 0; j < 5; ++j)
        *(float4*)&s_xm[(kk * 25 + s0 + j) * 52 + og] = make_float4(a[j][0], a[j][1], a[j][2], a[j][3]);
    }
    __syncthreads();
    // scatter: tile 5t x 4o, K-slice 32 (8 steps of 4 sk)
    if (tid < 240) {
      #pragma unroll
      for (int st = 0; st < 8; ++st) {
        const int sk0 = kbase + st * 4;
        float4 m0 = *(const float4*)&s_xm[(sk0 + 0) * 52 + o0];
        float4 m1 = *(const float4*)&s_xm[(sk0 + 1) * 52 + o0];
        float4 m2 = *(const float4*)&s_xm[(sk0 + 2) * 52 + o0];
        float4 m3 = *(const float4*)&s_xm[(sk0 + 3) * 52 + o0];
        #pragma unroll
        for (int tt = 0; tt < 5; ++tt) {
          float4 wv = *(const float4*)&s_w[(t0 + tt) * 128 + sk0];
          acc[tt][0] = fmaf(wv.x, m0.x, acc[tt][0]); acc[tt][1] = fmaf(wv.x, m0.y, acc[tt][1]);
          acc[tt][2] = fmaf(wv.x, m0.z, acc[tt][2]); acc[tt][3] = fmaf(wv.x, m0.w, acc[tt][3]);
          acc[tt][0] = fmaf(wv.y, m1.x, acc[tt][0]); acc[tt][1] = fmaf(wv.y, m1.y, acc[tt][1]);
          acc[tt][2] = fmaf(wv.y, m1.z, acc[tt][2]); acc[tt][3] = fmaf(wv.y, m1.w, acc[tt][3]);
          acc[tt][0] = fmaf(wv.z, m2.x, acc[tt][0]); acc[tt][1] = fmaf(wv.z, m2.y, acc[tt][1]);
          acc[tt][2] = fmaf(wv.z, m2.z, acc[tt][2]); acc[tt][3] = fmaf(wv.z, m2.w, acc[tt][3]);
          acc[tt][0] = fmaf(wv.w, m3.x, acc[tt][0]); acc[tt][1] = fmaf(wv.w, m3.y, acc[tt][1]);
          acc[tt][2] = fmaf(wv.w, m3.z, acc[tt][2]); acc[tt][3] = fmaf(wv.w, m3.w, acc[tt][3]);
        }
      }
    }
    __syncthreads();
  }

  // reduce K-split partials (alias s_xm as red[4][1200]) + root + bias + elu
  float* s_redp = s_xm;
  if (tid < 240) {
    #pragma unroll
    for (int tt = 0; tt < 5; ++tt)
      *(float4*)&s_redp[sks * 1200 + (t0 + tt) * 48 + o0] =
          make_float4(acc[tt][0], acc[tt][1], acc[tt][2], acc[tt][3]);
  }
  __syncthreads();
  for (int e = tid; e < 1200; e += 320) {
    int t = e / 48, o = e % 48;
    float v = s_redp[e] + s_redp[1200 + e] + s_redp[2400 + e] + s_redp[3600 + e];
    v *= s_ideg[t];
    #pragma unroll 8
    for (int i = 0; i < 32; ++i) v = fmaf(s_xT[i * 28 + t], root[i * 48 + o], v);
    xout[b * 1200 + e] = eluf(v + bias[o]);
  }
}

// ---------------- conv3: n=75, fin=16, K=25, cout=1, tanh ----------------
__global__ __launch_bounds__(384) void conv3_kernel(
    const float* __restrict__ x, const float* __restrict__ pos,
    const float* __restrict__ g, const float* __restrict__ mu, const float* __restrict__ sig,
    const float* __restrict__ root, const float* __restrict__ bias,
    float* __restrict__ xout)
{
  const int b = blockIdx.x, tid = threadIdx.x;
  __shared__ __align__(8) float2 s_u[75 * 75];   // [t][s] doubled diffs; sentinel {1e18,0}
  __shared__ float s_xm[75 * 28];                // [s][k] pad 28
  __shared__ float s_x[75 * 16];
  __shared__ float s_g3[400];
  __shared__ float s_pos[150];
  __shared__ float s_ek[25 * 5];                 // per-k {n0,n1,e0,e1,f}
  __shared__ float s_ideg[75];
  __shared__ float s_out[75];
  __shared__ float s_r3[16];

  if (tid < 150) s_pos[tid] = pos[b * 150 + tid];
  for (int e = tid; e < 1200; e += 384) s_x[e] = x[b * 1200 + e];
  for (int e = tid; e < 400; e += 384) s_g3[e] = g[e];
  if (tid < 25) {
    float m0 = mu[2 * tid], m1 = mu[2 * tid + 1];
    float sg0 = sig[2 * tid], sg1 = sig[2 * tid + 1];
    float n0 = NLOG2E_HALF / (sg0 * sg0 + 1e-15f);
    float n1 = NLOG2E_HALF / (sg1 * sg1 + 1e-15f);
    float c0 = 0.5f - m0, c1 = 0.5f - m1;
    s_ek[tid * 5 + 0] = n0;
    s_ek[tid * 5 + 1] = n1;
    s_ek[tid * 5 + 2] = 2.f * n0 * c0;
    s_ek[tid * 5 + 3] = 2.f * n1 * c1;
    s_ek[tid * 5 + 4] = n0 * c0 * c0 + n1 * c1 * c1;
  }
  if (tid < 16) s_r3[tid] = root[tid];
  if (tid < 75) s_out[tid] = 0.f;
  __syncthreads();

  for (int e = tid; e < 1875; e += 384) {
    int s = e / 25, k = e % 25;
    float a = 0.f;
    #pragma unroll
    for (int i = 0; i < 16; ++i) a = fmaf(s_x[s * 16 + i], s_g3[i * 25 + k], a);
    s_xm[s * 28 + k] = a;
  }
  for (int e = tid; e < 5625; e += 384) {
    int t = e / 75, s = e % 75;
    float d0 = s_pos[t * 2]     - s_pos[s * 2];
    float d1 = s_pos[t * 2 + 1] - s_pos[s * 2 + 1];
    float e0 = d0 + 1e-12f, e1 = d1 + 1e-12f;
    bool m = (e0 * e0 + e1 * e1 < 0.25f) && (s != t);
    s_u[e] = m ? make_float2(2.f * d0, 2.f * d1) : make_float2(1e18f, 0.f);
  }
  if (tid < 75) {
    int t = tid, c = 0;
    for (int s = 0; s < 75; ++s) {
      if (s == t) continue;
      float d0 = s_pos[t * 2]     - s_pos[s * 2]     + 1e-12f;
      float d1 = s_pos[t * 2 + 1] - s_pos[s * 2 + 1] + 1e-12f;
      c += (d0 * d0 + d1 * d1 < 0.25f) ? 1 : 0;
    }
    s_ideg[t] = 1.f / (float)(c < 1 ? 1 : c);
  }
  __syncthreads();

  // main: task = (t, kgroup of 5 k); ar = n0*u0^2 + n1*u1^2 + e0*u0 + e1*u1 + f
  if (tid < 375) {
    const int t = tid / 5, kg = tid % 5;
    float n0[5], n1[5], e0[5], e1[5], f[5];
    #pragma unroll
    for (int j = 0; j < 5; ++j) {
      int k = kg * 5 + j;
      n0[j] = s_ek[k * 5 + 0]; n1[j] = s_ek[k * 5 + 1];
      e0[j] = s_ek[k * 5 + 2]; e1[j] = s_ek[k * 5 + 3];
      f[j]  = s_ek[k * 5 + 4];
    }
    float acc[5] = {0.f, 0.f, 0.f, 0.f, 0.f};
    for (int s = 0; s < 75; ++s) {
      float2 uv = s_u[t * 75 + s];
      float u00 = uv.x * uv.x, u11 = uv.y * uv.y;
      #pragma unroll
      for (int j = 0; j < 5; ++j) {
        float ar = fmaf(u00, n0[j], fmaf(u11, n1[j], fmaf(uv.x, e0[j], fmaf(uv.y, e1[j], f[j]))));
        acc[j] = fmaf(exp2f(ar), s_xm[s * 28 + kg * 5 + j], acc[j]);
      }
    }
    float sum = acc[0] + acc[1] + acc[2] + acc[3] + acc[4];
    atomicAdd(&s_out[t], sum);
  }
  __syncthreads();

  if (tid < 75) {
    int t = tid;
    float r = 0.f;
    #pragma unroll
    for (int i = 0; i < 16; ++i) r = fmaf(s_x[t * 16 + i], s_r3[i], r);
    xout[b * 75 + t] = tanhf(s_out[t] * s_ideg[t] + r + bias[0]);
  }
}

// ---------------- MLP: [2+fdim] -> 128 -> 64 -> 2, elu everywhere ----------------
__global__ __launch_bounds__(256) void mlp_kernel(
    const float* __restrict__ pos_src, const float* __restrict__ feat,
    const float* __restrict__ w1, const float* __restrict__ b1,
    const float* __restrict__ w2, const float* __restrict__ b2,
    const float* __restrict__ w3, const float* __restrict__ b3,
    float* __restrict__ out, int fdim, int rep)
{
  const int tid = threadIdx.x;
  const int row0 = blockIdx.x * 64;
  const int din = fdim + 2;
  __shared__ __align__(16) float s_inT[34][68];
  __shared__ __align__(16) float s_h1T[128][68];
  __shared__ __align__(16) float s_h2T[64][68];

  if (tid < 128) {
    int r = tid >> 1, d = tid & 1;
    s_inT[d][r] = pos_src[((row0 + r) / rep) * 2 + d];
  }
  for (int e = tid; e < 64 * fdim; e += 256) {
    int r = e / fdim, c = e % fdim;
    s_inT[2 + c][r] = feat[(row0 + r) * fdim + c];
  }
  __syncthreads();

  {
    const int rb = tid >> 4, jb = tid & 15;
    const int r0 = rb << 2, j0 = jb << 3;
    float acc[4][8];
    #pragma unroll
    for (int jj = 0; jj < 8; ++jj) {
      float bv = b1[j0 + jj];
      acc[0][jj] = bv; acc[1][jj] = bv; acc[2][jj] = bv; acc[3][jj] = bv;
    }
    for (int i = 0; i < din; ++i) {
      float4 xa = *(const float4*)&s_inT[i][r0];
      float4 wa = *(const float4*)(w1 + i * 128 + j0);
      float4 wb = *(const float4*)(w1 + i * 128 + j0 + 4);
      float wv[8] = {wa.x, wa.y, wa.z, wa.w, wb.x, wb.y, wb.z, wb.w};
      #pragma unroll
      for (int jj = 0; jj < 8; ++jj) {
        acc[0][jj] = fmaf(xa.x, wv[jj], acc[0][jj]);
        acc[1][jj] = fmaf(xa.y, wv[jj], acc[1][jj]);
        acc[2][jj] = fmaf(xa.z, wv[jj], acc[2][jj]);
        acc[3][jj] = fmaf(xa.w, wv[jj], acc[3][jj]);
      }
    }
    #pragma unroll
    for (int jj = 0; jj < 8; ++jj)
      *(float4*)&s_h1T[j0 + jj][r0] =
        make_float4(eluf(acc[0][jj]), eluf(acc[1][jj]), eluf(acc[2][jj]), eluf(acc[3][jj]));
  }
  __syncthreads();

  {
    const int rb = tid >> 4, jb = tid & 15;
    const int r0 = rb << 2, j0 = jb << 2;
    float acc[4][4];
    #pragma unroll
    for (int jj = 0; jj < 4; ++jj) {
      float bv = b2[j0 + jj];
      acc[0][jj] = bv; acc[1][jj] = bv; acc[2][jj] = bv; acc[3][jj] = bv;
    }
    #pragma unroll 4
    for (int i = 0; i < 128; ++i) {
      float4 ha = *(const float4*)&s_h1T[i][r0];
      float4 wa = *(const float4*)(w2 + i * 64 + j0);
      float wv[4] = {wa.x, wa.y, wa.z, wa.w};
      #pragma unroll
      for (int jj = 0; jj < 4; ++jj) {
        acc[0][jj] = fmaf(ha.x, wv[jj], acc[0][jj]);
        acc[1][jj] = fmaf(ha.y, wv[jj], acc[1][jj]);
        acc[2][jj] = fmaf(ha.z, wv[jj], acc[2][jj]);
        acc[3][jj] = fmaf(ha.w, wv[jj], acc[3][jj]);
      }
    }
    #pragma unroll
    for (int jj = 0; jj < 4; ++jj)
      *(float4*)&s_h2T[j0 + jj][r0] =
        make_float4(eluf(acc[0][jj]), eluf(acc[1][jj]), eluf(acc[2][jj]), eluf(acc[3][jj]));
  }
  __syncthreads();

  if (tid < 128) {
    int r = tid >> 1, c = tid & 1;
    float a = b3[c];
    #pragma unroll 8
    for (int j = 0; j < 64; ++j)
      a = fmaf(s_h2T[j][r], w3[j * 2 + c], a);
    out[(row0 + r) * 2 + c] = eluf(a);
  }
}

extern "C" void kernel_launch(void* const* d_in, const int* in_sizes, int n_in,
                              void* d_out, int out_size, void* d_ws, size_t ws_size,
                              hipStream_t stream)
{
  const float* x     = (const float*)d_in[0];
  const float* pos   = (const float*)d_in[1];
  const float* g1    = (const float*)d_in[2];
  const float* mu1   = (const float*)d_in[3];
  const float* sig1  = (const float*)d_in[4];
  const float* root1 = (const float*)d_in[5];
  const float* cb1   = (const float*)d_in[6];
  const float* g2    = (const float*)d_in[7];
  const float* mu2   = (const float*)d_in[8];
  const float* sig2  = (const float*)d_in[9];
  const float* root2 = (const float*)d_in[10];
  const float* cb2   = (const float*)d_in[11];
  const float* g3    = (const float*)d_in[12];
  const float* mu3   = (const float*)d_in[13];
  const float* sig3  = (const float*)d_in[14];
  const float* root3 = (const float*)d_in[15];
  const float* cb3   = (const float*)d_in[16];
  const float* p1w1  = (const float*)d_in[17];
  const float* p1b1  = (const float*)d_in[18];
  const float* p1w2  = (const float*)d_in[19];
  const float* p1b2  = (const float*)d_in[20];
  const float* p1w3  = (const float*)d_in[21];
  const float* p1b3  = (const float*)d_in[22];
  const float* p2w1  = (const float*)d_in[23];
  const float* p2b1  = (const float*)d_in[24];
  const float* p2w2  = (const float*)d_in[25];
  const float* p2b2  = (const float*)d_in[26];
  const float* p2w3  = (const float*)d_in[27];
  const float* p2b3  = (const float*)d_in[28];

  float* out  = (float*)d_out;
  float* ws   = (float*)d_ws;
  float* x1   = ws;            // 5120*160 = 819200 floats
  float* pos1 = ws + 819200;   // 25600*2  = 51200
  float* x2   = ws + 870400;   // 76800*16 = 1228800
  float* x3   = out;           // 76800
  float* pos2 = out + 76800;   // 76800*2

  conv1_kernel<<<dim3(512), dim3(512), 0, stream>>>(x, pos, g1, mu1, sig1, root1, cb1, x1);
  mlp_kernel<<<dim3(400), dim3(256), 0, stream>>>(pos, x1, p1w1, p1b1, p1w2, p1b2, p1w3, p1b3,
                                                  pos1, 32, 5);
  conv2_kernel<<<dim3(1024), dim3(320), 0, stream>>>(x1, pos1, g2, mu2, sig2, root2, cb2, x2);
  mlp_kernel<<<dim3(1200), dim3(256), 0, stream>>>(pos1, x2, p2w1, p2b1, p2w2, p2b2, p2w3, p2b3,
                                                  pos2, 16, 3);
  conv3_kernel<<<dim3(1024), dim3(384), 0, stream>>>(x2, pos2, g3, mu3, sig3, root3, cb3, x3);
}

// Round 4
// 336.624 us; speedup vs baseline: 1.6225x; 1.0496x over previous
//
#include <hip/hip_runtime.h>
#include <math.h>

// GaussianGenerator v4: conv2 rebuilt as balanced 3-phase chunked kernel
// (u-table wgen, 300/300 thread-balanced GEMM+scatter, conflict-free W pad).
// conv1/conv3/MLP unchanged from v3. All fp32 (pos chain is mask-critical).

__device__ __forceinline__ float eluf(float v) { return v > 0.f ? v : __expf(v) - 1.f; }

#define NLOG2E_HALF (-0.72134752f)   // -0.5*log2(e)

// ---------------- conv1: n=5, fin=64, K=25, cout=160; 2 graphs/block ----------------
__global__ __launch_bounds__(512) void conv1_kernel(
    const float* __restrict__ x, const float* __restrict__ pos,
    const float* __restrict__ g, const float* __restrict__ mu, const float* __restrict__ sig,
    const float* __restrict__ root, const float* __restrict__ bias,
    float* __restrict__ xout)
{
  const int b = blockIdx.x, tid = threadIdx.x;
  __shared__ __align__(16) float s_xT[64 * 12];          // [i][r], r=g*5+s (10, pad 12)
  __shared__ __align__(16) float s_xm[10 * 832];         // chunk GEMM out [r][<=800]; cols 800..831 zero
  __shared__ __align__(16) float s_w[2 * 5 * 5 * 28];    // [g][t][ch][28] (slots 25..27 zero)
  __shared__ __align__(16) float s_red[2 * 2 * 5 * 160]; // [ks][g][t][o]
  __shared__ float s_pos[20];
  __shared__ float s_msc[25][4];
  __shared__ float s_ideg[10];

  if (tid < 20) s_pos[tid] = pos[b * 20 + tid];
  if (tid < 25) {
    float m0 = mu[2 * tid], m1 = mu[2 * tid + 1];
    float s0 = sig[2 * tid], s1 = sig[2 * tid + 1];
    s_msc[tid][0] = 0.5f - m0;
    s_msc[tid][1] = 0.5f - m1;
    s_msc[tid][2] = NLOG2E_HALF / (s0 * s0 + 1e-15f);
    s_msc[tid][3] = NLOG2E_HALF / (s1 * s1 + 1e-15f);
  }
  for (int e = tid; e < 640; e += 512) { int nd = e >> 6, i = e & 63; s_xT[i * 12 + nd] = x[b * 640 + nd * 64 + i]; }
  for (int e = tid; e < 320; e += 512) { int r = e / 32, c = e % 32; s_xm[r * 832 + 800 + c] = 0.f; }
  __syncthreads();

  if (tid < 10) {
    int gg = tid / 5, t = tid % 5, c = 0;
    for (int s = 0; s < 5; ++s) {
      if (s == t) continue;
      float d0 = s_pos[(gg * 5 + t) * 2]     - s_pos[(gg * 5 + s) * 2]     + 1e-12f;
      float d1 = s_pos[(gg * 5 + t) * 2 + 1] - s_pos[(gg * 5 + s) * 2 + 1] + 1e-12f;
      c += (d0 * d0 + d1 * d1 < 0.25f) ? 1 : 0;
    }
    s_ideg[tid] = 1.f / (float)(c < 1 ? 1 : c);
  }
  // W[g][t][ch][skl], skl = kk*5+s (k = ch*5+kk), zero-padded 25..27
  for (int e = tid; e < 1400; e += 512) {
    int gg = e / 700, r2 = e % 700, t = r2 / 140, c = r2 % 140;
    int ch = c / 28, skl = c % 28;
    float wv = 0.f;
    if (skl < 25) {
      int kk = skl / 5, s = skl % 5, k = ch * 5 + kk;
      float d0 = s_pos[(gg * 5 + t) * 2]     - s_pos[(gg * 5 + s) * 2];
      float d1 = s_pos[(gg * 5 + t) * 2 + 1] - s_pos[(gg * 5 + s) * 2 + 1];
      float e0 = d0 + 1e-12f, e1 = d1 + 1e-12f;
      bool m = (e0 * e0 + e1 * e1 < 0.25f) && (s != t);
      float q0 = fmaf(2.f, d0, s_msc[k][0]);
      float q1 = fmaf(2.f, d1, s_msc[k][1]);
      float a = q0 * q0 * s_msc[k][2];
      a = fmaf(q1 * q1, s_msc[k][3], a);
      wv = m ? exp2f(a) : 0.f;
    }
    s_w[e] = wv;
  }
  __syncthreads();

  float sacc[5][2];
  #pragma unroll
  for (int t = 0; t < 5; ++t) { sacc[t][0] = 0.f; sacc[t][1] = 0.f; }
  const int sg = tid / 160, sr = tid % 160, sks = sr / 80, sob = sr % 80;
  const int so0 = sob * 2;

  for (int ch = 0; ch < 5; ++ch) {
    // GEMM: 10r x 2c tiles over 800 cols (5k x 160o), K=64
    if (tid < 400) {
      const int c0 = tid * 2;
      const float* gp = g + ch * 800 + c0;
      float a[10][2];
      #pragma unroll
      for (int r = 0; r < 10; ++r) { a[r][0] = 0.f; a[r][1] = 0.f; }
      #pragma unroll 4
      for (int i = 0; i < 64; ++i) {
        float2 gv = *(const float2*)(gp + i * 4000);
        float4 xa = *(const float4*)&s_xT[i * 12];
        float4 xb = *(const float4*)&s_xT[i * 12 + 4];
        float2 xc = *(const float2*)&s_xT[i * 12 + 8];
        a[0][0] = fmaf(xa.x, gv.x, a[0][0]); a[0][1] = fmaf(xa.x, gv.y, a[0][1]);
        a[1][0] = fmaf(xa.y, gv.x, a[1][0]); a[1][1] = fmaf(xa.y, gv.y, a[1][1]);
        a[2][0] = fmaf(xa.z, gv.x, a[2][0]); a[2][1] = fmaf(xa.z, gv.y, a[2][1]);
        a[3][0] = fmaf(xa.w, gv.x, a[3][0]); a[3][1] = fmaf(xa.w, gv.y, a[3][1]);
        a[4][0] = fmaf(xb.x, gv.x, a[4][0]); a[4][1] = fmaf(xb.x, gv.y, a[4][1]);
        a[5][0] = fmaf(xb.y, gv.x, a[5][0]); a[5][1] = fmaf(xb.y, gv.y, a[5][1]);
        a[6][0] = fmaf(xb.z, gv.x, a[6][0]); a[6][1] = fmaf(xb.z, gv.y, a[6][1]);
        a[7][0] = fmaf(xb.w, gv.x, a[7][0]); a[7][1] = fmaf(xb.w, gv.y, a[7][1]);
        a[8][0] = fmaf(xc.x, gv.x, a[8][0]); a[8][1] = fmaf(xc.x, gv.y, a[8][1]);
        a[9][0] = fmaf(xc.y, gv.x, a[9][0]); a[9][1] = fmaf(xc.y, gv.y, a[9][1]);
      }
      #pragma unroll
      for (int r = 0; r < 10; ++r)
        *(float2*)&s_xm[r * 832 + c0] = make_float2(a[r][0], a[r][1]);
    }
    __syncthreads();
    // scatter: tile 5t x 2o, K-split 2 (slice 16 / 12+pad); compile-time sk decode
    if (tid < 320) {
#define C1_STEP(SK0) { \
      float2 m0 = *(const float2*)&s_xm[(sg * 5 + ((SK0) % 5)) * 832 + ((SK0) / 5) * 160 + so0]; \
      float2 m1 = *(const float2*)&s_xm[(sg * 5 + (((SK0) + 1) % 5)) * 832 + (((SK0) + 1) / 5) * 160 + so0]; \
      float2 m2 = *(const float2*)&s_xm[(sg * 5 + (((SK0) + 2) % 5)) * 832 + (((SK0) + 2) / 5) * 160 + so0]; \
      float2 m3 = *(const float2*)&s_xm[(sg * 5 + (((SK0) + 3) % 5)) * 832 + (((SK0) + 3) / 5) * 160 + so0]; \
      _Pragma("unroll") \
      for (int t = 0; t < 5; ++t) { \
        const float4 wv = *(const float4*)&s_w[((sg * 5 + t) * 5 + ch) * 28 + (SK0)]; \
        sacc[t][0] = fmaf(wv.x, m0.x, sacc[t][0]); sacc[t][1] = fmaf(wv.x, m0.y, sacc[t][1]); \
        sacc[t][0] = fmaf(wv.y, m1.x, sacc[t][0]); sacc[t][1] = fmaf(wv.y, m1.y, sacc[t][1]); \
        sacc[t][0] = fmaf(wv.z, m2.x, sacc[t][0]); sacc[t][1] = fmaf(wv.z, m2.y, sacc[t][1]); \
        sacc[t][0] = fmaf(wv.w, m3.x, sacc[t][0]); sacc[t][1] = fmaf(wv.w, m3.y, sacc[t][1]); \
      } }
      if (sks == 0) { C1_STEP(0) C1_STEP(4) C1_STEP(8) C1_STEP(12) }
      else          { C1_STEP(16) C1_STEP(20) C1_STEP(24) }
#undef C1_STEP
    }
    __syncthreads();
  }

  // root chunk: XM_root[r][o<160] = x @ root (tile 2r x 2c)
  if (tid < 400) {
    const int rb = tid / 80, cb = tid % 80;
    const int r0 = rb * 2, c0 = cb * 2;
    float a00 = 0.f, a01 = 0.f, a10 = 0.f, a11 = 0.f;
    #pragma unroll 4
    for (int i = 0; i < 64; ++i) {
      float2 rv = *(const float2*)(root + i * 160 + c0);
      float2 xv = *(const float2*)&s_xT[i * 12 + r0];
      a00 = fmaf(xv.x, rv.x, a00); a01 = fmaf(xv.x, rv.y, a01);
      a10 = fmaf(xv.y, rv.x, a10); a11 = fmaf(xv.y, rv.y, a11);
    }
    *(float2*)&s_xm[r0 * 832 + c0]       = make_float2(a00, a01);
    *(float2*)&s_xm[(r0 + 1) * 832 + c0] = make_float2(a10, a11);
  }
  if (tid < 320) {
    #pragma unroll
    for (int t = 0; t < 5; ++t) {
      s_red[((sks * 2 + sg) * 5 + t) * 160 + so0]     = sacc[t][0];
      s_red[((sks * 2 + sg) * 5 + t) * 160 + so0 + 1] = sacc[t][1];
    }
  }
  __syncthreads();
  for (int e = tid; e < 1600; e += 512) {
    int gg = e / 800, r2 = e % 800, t = r2 / 160, o = r2 % 160;
    float v = s_red[(gg * 5 + t) * 160 + o] + s_red[((2 + gg) * 5 + t) * 160 + o];
    v = v * s_ideg[gg * 5 + t] + s_xm[(gg * 5 + t) * 832 + o] + bias[o];
    xout[b * 1600 + e] = eluf(v);
  }
}

// ---------------- conv2 v4: n=25, fin=32, K=25, cout=48 ----------------
// Balanced 3-phase chunks (kc=5): wgen(u-table) + GEMM(300thr) | scatter(300thr).
__global__ __launch_bounds__(320) void conv2_kernel(
    const float* __restrict__ x, const float* __restrict__ pos,
    const float* __restrict__ g, const float* __restrict__ mu, const float* __restrict__ sig,
    const float* __restrict__ root, const float* __restrict__ bias,
    float* __restrict__ xout)
{
  const int b = blockIdx.x, tid = threadIdx.x;
  __shared__ __align__(16) float s_xT[32 * 28];    // [i][s], pad 28
  __shared__ __align__(16) float s_xm[125 * 52];   // [sk][o pad52]; aliased as red[5][1200] at end
  __shared__ __align__(16) float s_w[25 * 132];    // [t][sk pad132] (bank-safe: 5*132%32=20)
  __shared__ __align__(8)  float2 s_u[25 * 26];    // [t][s pad26] masked doubled diffs
  __shared__ float s_ek[25 * 5];                   // per-k {n0,n1,e0,e1,f}
  __shared__ float s_pos[50];
  __shared__ float s_ideg[25];

  if (tid < 50) s_pos[tid] = pos[b * 50 + tid];
  if (tid < 25) {
    float m0 = mu[2 * tid], m1 = mu[2 * tid + 1];
    float sg0 = sig[2 * tid], sg1 = sig[2 * tid + 1];
    float n0 = NLOG2E_HALF / (sg0 * sg0 + 1e-15f);
    float n1 = NLOG2E_HALF / (sg1 * sg1 + 1e-15f);
    float c0 = 0.5f - m0, c1 = 0.5f - m1;
    s_ek[tid * 5 + 0] = n0;
    s_ek[tid * 5 + 1] = n1;
    s_ek[tid * 5 + 2] = 2.f * n0 * c0;
    s_ek[tid * 5 + 3] = 2.f * n1 * c1;
    s_ek[tid * 5 + 4] = fmaf(n0, c0 * c0, n1 * c1 * c1);
  }
  for (int e = tid; e < 800; e += 320) { int r = e / 32, i = e % 32; s_xT[i * 28 + r] = x[b * 800 + e]; }
  __syncthreads();

  // u-table (mask folded as sentinel) + degree
  for (int e = tid; e < 625; e += 320) {
    int t = e / 25, s = e % 25;
    float d0 = s_pos[t * 2]     - s_pos[s * 2];
    float d1 = s_pos[t * 2 + 1] - s_pos[s * 2 + 1];
    float e0 = d0 + 1e-12f, e1 = d1 + 1e-12f;
    bool m = (e0 * e0 + e1 * e1 < 0.25f) && (s != t);
    s_u[t * 26 + s] = m ? make_float2(2.f * d0, 2.f * d1) : make_float2(1e18f, 0.f);
  }
  if (tid < 25) {
    int t = tid, c = 0;
    for (int s = 0; s < 25; ++s) {
      if (s == t) continue;
      float d0 = s_pos[t * 2]     - s_pos[s * 2]     + 1e-12f;
      float d1 = s_pos[t * 2 + 1] - s_pos[s * 2 + 1] + 1e-12f;
      c += (d0 * d0 + d1 * d1 < 0.25f) ? 1 : 0;
    }
    s_ideg[t] = 1.f / (float)(c < 1 ? 1 : c);
  }
  __syncthreads();

  // roles: tid -> (grp = tid/60, tg = (tid%60)/12, og = tid%12); active if tid<300
  const bool act = tid < 300;
  const int grp = tid / 60, rr = tid % 60, tg = rr / 12, og = rr % 12;
  const int o0 = og * 4;
  // scatter: ks = grp (K-split over 25 sk each), t0 = tg*5
  // GEMM:    kk = grp, s0 = tg*5
  const int t0 = tg * 5, sk0 = grp * 25, s0 = tg * 5;

  float acc2[5][4];
  #pragma unroll
  for (int tt = 0; tt < 5; ++tt) { acc2[tt][0] = acc2[tt][1] = acc2[tt][2] = acc2[tt][3] = 0.f; }

  for (int ch = 0; ch < 5; ++ch) {
    const int k0 = ch * 5;
    // wgen: W[t][kk*25+s] via u-table + expanded quadratic (masked -> exp2(-1e36)=0)
    for (int e = tid; e < 3125; e += 320) {
      int t = e / 125, c = e % 125;
      int kk = c / 25, s = c % 25, k = k0 + kk;
      float2 uv = s_u[t * 26 + s];
      const float* ekp = &s_ek[k * 5];
      float ar = fmaf(uv.x * uv.x, ekp[0],
                 fmaf(uv.y * uv.y, ekp[1],
                 fmaf(uv.x, ekp[2],
                 fmaf(uv.y, ekp[3], ekp[4]))));
      s_w[t * 132 + c] = exp2f(ar);
    }
    // GEMM: XM[kk*25+s][o] = sum_i x[s][i] * g[i][(k0+kk)*48+o]; tile 5s x 4o
    if (act) {
      const float* gp = g + (k0 + grp) * 48 + o0;
      float a[5][4];
      #pragma unroll
      for (int r = 0; r < 5; ++r) { a[r][0] = a[r][1] = a[r][2] = a[r][3] = 0.f; }
      #pragma unroll 4
      for (int i = 0; i < 32; ++i) {
        float4 gv = *(const float4*)(gp + i * 1200);
        float x0 = s_xT[i * 28 + s0];
        float x1 = s_xT[i * 28 + s0 + 1];
        float x2 = s_xT[i * 28 + s0 + 2];
        float x3 = s_xT[i * 28 + s0 + 3];
        float x4 = s_xT[i * 28 + s0 + 4];
        a[0][0] = fmaf(x0, gv.x, a[0][0]); a[0][1] = fmaf(x0, gv.y, a[0][1]);
        a[0][2] = fmaf(x0, gv.z, a[0][2]); a[0][3] = fmaf(x0, gv.w, a[0][3]);
        a[1][0] = fmaf(x1, gv.x, a[1][0]); a[1][1] = fmaf(x1, gv.y, a[1][1]);
        a[1][2] = fmaf(x1, gv.z, a[1][2]); a[1][3] = fmaf(x1, gv.w, a[1][3]);
        a[2][0] = fmaf(x2, gv.x, a[2][0]); a[2][1] = fmaf(x2, gv.y, a[2][1]);
        a[2][2] = fmaf(x2, gv.z, a[2][2]); a[2][3] = fmaf(x2, gv.w, a[2][3]);
        a[3][0] = fmaf(x3, gv.x, a[3][0]); a[3][1] = fmaf(x3, gv.y, a[3][1]);
        a[3][2] = fmaf(x3, gv.z, a[3][2]); a[3][3] = fmaf(x3, gv.w, a[3][3]);
        a[4][0] = fmaf(x4, gv.x, a[4][0]); a[4][1] = fmaf(x4, gv.y, a[4][1]);
        a[4][2] = fmaf(x4, gv.z, a[4][2]); a[4][3] = fmaf(x4, gv.w, a[4][3]);
      }
      #pragma unroll
      for (int j = 0; j < 5; ++j)
        *(float4*)&s_xm[(grp * 25 + s0 + j) * 52 + o0] = make_float4(a[j][0], a[j][1], a[j][2], a[j][3]);
    }
    __syncthreads();
    // scatter: acc2[5t][4o] += sum over this chunk's 125 sk, K-split 5 (25 sk each)
    if (act) {
      #pragma unroll 5
      for (int q = 0; q < 25; ++q) {
        const int sk = sk0 + q;
        float4 mv = *(const float4*)&s_xm[sk * 52 + o0];
        float w0 = s_w[(t0 + 0) * 132 + sk];
        float w1 = s_w[(t0 + 1) * 132 + sk];
        float w2 = s_w[(t0 + 2) * 132 + sk];
        float w3 = s_w[(t0 + 3) * 132 + sk];
        float w4 = s_w[(t0 + 4) * 132 + sk];
        acc2[0][0] = fmaf(w0, mv.x, acc2[0][0]); acc2[0][1] = fmaf(w0, mv.y, acc2[0][1]);
        acc2[0][2] = fmaf(w0, mv.z, acc2[0][2]); acc2[0][3] = fmaf(w0, mv.w, acc2[0][3]);
        acc2[1][0] = fmaf(w1, mv.x, acc2[1][0]); acc2[1][1] = fmaf(w1, mv.y, acc2[1][1]);
        acc2[1][2] = fmaf(w1, mv.z, acc2[1][2]); acc2[1][3] = fmaf(w1, mv.w, acc2[1][3]);
        acc2[2][0] = fmaf(w2, mv.x, acc2[2][0]); acc2[2][1] = fmaf(w2, mv.y, acc2[2][1]);
        acc2[2][2] = fmaf(w2, mv.z, acc2[2][2]); acc2[2][3] = fmaf(w2, mv.w, acc2[2][3]);
        acc2[3][0] = fmaf(w3, mv.x, acc2[3][0]); acc2[3][1] = fmaf(w3, mv.y, acc2[3][1]);
        acc2[3][2] = fmaf(w3, mv.z, acc2[3][2]); acc2[3][3] = fmaf(w3, mv.w, acc2[3][3]);
        acc2[4][0] = fmaf(w4, mv.x, acc2[4][0]); acc2[4][1] = fmaf(w4, mv.y, acc2[4][1]);
        acc2[4][2] = fmaf(w4, mv.z, acc2[4][2]); acc2[4][3] = fmaf(w4, mv.w, acc2[4][3]);
      }
    }
    __syncthreads();
  }

  // write K-split partials into red (alias s_xm: 5*1200 = 6000 <= 6500)
  if (act) {
    #pragma unroll
    for (int tt = 0; tt < 5; ++tt)
      *(float4*)&s_xm[grp * 1200 + (t0 + tt) * 48 + o0] =
          make_float4(acc2[tt][0], acc2[tt][1], acc2[tt][2], acc2[tt][3]);
  }
  __syncthreads();
  for (int e = tid; e < 1200; e += 320) {
    int t = e / 48, o = e % 48;
    float v = s_xm[e] + s_xm[1200 + e] + s_xm[2400 + e] + s_xm[3600 + e] + s_xm[4800 + e];
    v *= s_ideg[t];
    #pragma unroll 8
    for (int i = 0; i < 32; ++i) v = fmaf(s_xT[i * 28 + t], root[i * 48 + o], v);
    xout[b * 1200 + e] = eluf(v + bias[o]);
  }
}

// ---------------- conv3: n=75, fin=16, K=25, cout=1, tanh ----------------
__global__ __launch_bounds__(384) void conv3_kernel(
    const float* __restrict__ x, const float* __restrict__ pos,
    const float* __restrict__ g, const float* __restrict__ mu, const float* __restrict__ sig,
    const float* __restrict__ root, const float* __restrict__ bias,
    float* __restrict__ xout)
{
  const int b = blockIdx.x, tid = threadIdx.x;
  __shared__ __align__(8) float2 s_u[75 * 75];   // [t][s] doubled diffs; sentinel {1e18,0}
  __shared__ float s_xm[75 * 28];                // [s][k] pad 28
  __shared__ float s_x[75 * 16];
  __shared__ float s_g3[400];
  __shared__ float s_pos[150];
  __shared__ float s_ek[25 * 5];                 // per-k {n0,n1,e0,e1,f}
  __shared__ float s_ideg[75];
  __shared__ float s_out[75];
  __shared__ float s_r3[16];

  if (tid < 150) s_pos[tid] = pos[b * 150 + tid];
  for (int e = tid; e < 1200; e += 384) s_x[e] = x[b * 1200 + e];
  for (int e = tid; e < 400; e += 384) s_g3[e] = g[e];
  if (tid < 25) {
    float m0 = mu[2 * tid], m1 = mu[2 * tid + 1];
    float sg0 = sig[2 * tid], sg1 = sig[2 * tid + 1];
    float n0 = NLOG2E_HALF / (sg0 * sg0 + 1e-15f);
    float n1 = NLOG2E_HALF / (sg1 * sg1 + 1e-15f);
    float c0 = 0.5f - m0, c1 = 0.5f - m1;
    s_ek[tid * 5 + 0] = n0;
    s_ek[tid * 5 + 1] = n1;
    s_ek[tid * 5 + 2] = 2.f * n0 * c0;
    s_ek[tid * 5 + 3] = 2.f * n1 * c1;
    s_ek[tid * 5 + 4] = n0 * c0 * c0 + n1 * c1 * c1;
  }
  if (tid < 16) s_r3[tid] = root[tid];
  if (tid < 75) s_out[tid] = 0.f;
  __syncthreads();

  for (int e = tid; e < 1875; e += 384) {
    int s = e / 25, k = e % 25;
    float a = 0.f;
    #pragma unroll
    for (int i = 0; i < 16; ++i) a = fmaf(s_x[s * 16 + i], s_g3[i * 25 + k], a);
    s_xm[s * 28 + k] = a;
  }
  for (int e = tid; e < 5625; e += 384) {
    int t = e / 75, s = e % 75;
    float d0 = s_pos[t * 2]     - s_pos[s * 2];
    float d1 = s_pos[t * 2 + 1] - s_pos[s * 2 + 1];
    float e0 = d0 + 1e-12f, e1 = d1 + 1e-12f;
    bool m = (e0 * e0 + e1 * e1 < 0.25f) && (s != t);
    s_u[e] = m ? make_float2(2.f * d0, 2.f * d1) : make_float2(1e18f, 0.f);
  }
  if (tid < 75) {
    int t = tid, c = 0;
    for (int s = 0; s < 75; ++s) {
      if (s == t) continue;
      float d0 = s_pos[t * 2]     - s_pos[s * 2]     + 1e-12f;
      float d1 = s_pos[t * 2 + 1] - s_pos[s * 2 + 1] + 1e-12f;
      c += (d0 * d0 + d1 * d1 < 0.25f) ? 1 : 0;
    }
    s_ideg[t] = 1.f / (float)(c < 1 ? 1 : c);
  }
  __syncthreads();

  if (tid < 375) {
    const int t = tid / 5, kg = tid % 5;
    float n0[5], n1[5], e0[5], e1[5], f[5];
    #pragma unroll
    for (int j = 0; j < 5; ++j) {
      int k = kg * 5 + j;
      n0[j] = s_ek[k * 5 + 0]; n1[j] = s_ek[k * 5 + 1];
      e0[j] = s_ek[k * 5 + 2]; e1[j] = s_ek[k * 5 + 3];
      f[j]  = s_ek[k * 5 + 4];
    }
    float acc[5] = {0.f, 0.f, 0.f, 0.f, 0.f};
    for (int s = 0; s < 75; ++s) {
      float2 uv = s_u[t * 75 + s];
      float u00 = uv.x * uv.x, u11 = uv.y * uv.y;
      #pragma unroll
      for (int j = 0; j < 5; ++j) {
        float ar = fmaf(u00, n0[j], fmaf(u11, n1[j], fmaf(uv.x, e0[j], fmaf(uv.y, e1[j], f[j]))));
        acc[j] = fmaf(exp2f(ar), s_xm[s * 28 + kg * 5 + j], acc[j]);
      }
    }
    float sum = acc[0] + acc[1] + acc[2] + acc[3] + acc[4];
    atomicAdd(&s_out[t], sum);
  }
  __syncthreads();

  if (tid < 75) {
    int t = tid;
    float r = 0.f;
    #pragma unroll
    for (int i = 0; i < 16; ++i) r = fmaf(s_x[t * 16 + i], s_r3[i], r);
    xout[b * 75 + t] = tanhf(s_out[t] * s_ideg[t] + r + bias[0]);
  }
}

// ---------------- MLP: [2+fdim] -> 128 -> 64 -> 2, elu everywhere ----------------
__global__ __launch_bounds__(256) void mlp_kernel(
    const float* __restrict__ pos_src, const float* __restrict__ feat,
    const float* __restrict__ w1, const float* __restrict__ b1,
    const float* __restrict__ w2, const float* __restrict__ b2,
    const float* __restrict__ w3, const float* __restrict__ b3,
    float* __restrict__ out, int fdim, int rep)
{
  const int tid = threadIdx.x;
  const int row0 = blockIdx.x * 64;
  const int din = fdim + 2;
  __shared__ __align__(16) float s_inT[34][68];
  __shared__ __align__(16) float s_h1T[128][68];
  __shared__ __align__(16) float s_h2T[64][68];

  if (tid < 128) {
    int r = tid >> 1, d = tid & 1;
    s_inT[d][r] = pos_src[((row0 + r) / rep) * 2 + d];
  }
  for (int e = tid; e < 64 * fdim; e += 256) {
    int r = e / fdim, c = e % fdim;
    s_inT[2 + c][r] = feat[(row0 + r) * fdim + c];
  }
  __syncthreads();

  {
    const int rb = tid >> 4, jb = tid & 15;
    const int r0 = rb << 2, j0 = jb << 3;
    float acc[4][8];
    #pragma unroll
    for (int jj = 0; jj < 8; ++jj) {
      float bv = b1[j0 + jj];
      acc[0][jj] = bv; acc[1][jj] = bv; acc[2][jj] = bv; acc[3][jj] = bv;
    }
    for (int i = 0; i < din; ++i) {
      float4 xa = *(const float4*)&s_inT[i][r0];
      float4 wa = *(const float4*)(w1 + i * 128 + j0);
      float4 wb = *(const float4*)(w1 + i * 128 + j0 + 4);
      float wv[8] = {wa.x, wa.y, wa.z, wa.w, wb.x, wb.y, wb.z, wb.w};
      #pragma unroll
      for (int jj = 0; jj < 8; ++jj) {
        acc[0][jj] = fmaf(xa.x, wv[jj], acc[0][jj]);
        acc[1][jj] = fmaf(xa.y, wv[jj], acc[1][jj]);
        acc[2][jj] = fmaf(xa.z, wv[jj], acc[2][jj]);
        acc[3][jj] = fmaf(xa.w, wv[jj], acc[3][jj]);
      }
    }
    #pragma unroll
    for (int jj = 0; jj < 8; ++jj)
      *(float4*)&s_h1T[j0 + jj][r0] =
        make_float4(eluf(acc[0][jj]), eluf(acc[1][jj]), eluf(acc[2][jj]), eluf(acc[3][jj]));
  }
  __syncthreads();

  {
    const int rb = tid >> 4, jb = tid & 15;
    const int r0 = rb << 2, j0 = jb << 2;
    float acc[4][4];
    #pragma unroll
    for (int jj = 0; jj < 4; ++jj) {
      float bv = b2[j0 + jj];
      acc[0][jj] = bv; acc[1][jj] = bv; acc[2][jj] = bv; acc[3][jj] = bv;
    }
    #pragma unroll 4
    for (int i = 0; i < 128; ++i) {
      float4 ha = *(const float4*)&s_h1T[i][r0];
      float4 wa = *(const float4*)(w2 + i * 64 + j0);
      float wv[4] = {wa.x, wa.y, wa.z, wa.w};
      #pragma unroll
      for (int jj = 0; jj < 4; ++jj) {
        acc[0][jj] = fmaf(ha.x, wv[jj], acc[0][jj]);
        acc[1][jj] = fmaf(ha.y, wv[jj], acc[1][jj]);
        acc[2][jj] = fmaf(ha.z, wv[jj], acc[2][jj]);
        acc[3][jj] = fmaf(ha.w, wv[jj], acc[3][jj]);
      }
    }
    #pragma unroll
    for (int jj = 0; jj < 4; ++jj)
      *(float4*)&s_h2T[j0 + jj][r0] =
        make_float4(eluf(acc[0][jj]), eluf(acc[1][jj]), eluf(acc[2][jj]), eluf(acc[3][jj]));
  }
  __syncthreads();

  if (tid < 128) {
    int r = tid >> 1, c = tid & 1;
    float a = b3[c];
    #pragma unroll 8
    for (int j = 0; j < 64; ++j)
      a = fmaf(s_h2T[j][r], w3[j * 2 + c], a);
    out[(row0 + r) * 2 + c] = eluf(a);
  }
}

extern "C" void kernel_launch(void* const* d_in, const int* in_sizes, int n_in,
                              void* d_out, int out_size, void* d_ws, size_t ws_size,
                              hipStream_t stream)
{
  const float* x     = (const float*)d_in[0];
  const float* pos   = (const float*)d_in[1];
  const float* g1    = (const float*)d_in[2];
  const float* mu1   = (const float*)d_in[3];
  const float* sig1  = (const float*)d_in[4];
  const float* root1 = (const float*)d_in[5];
  const float* cb1   = (const float*)d_in[6];
  const float* g2    = (const float*)d_in[7];
  const float* mu2   = (const float*)d_in[8];
  const float* sig2  = (const float*)d_in[9];
  const float* root2 = (const float*)d_in[10];
  const float* cb2   = (const float*)d_in[11];
  const float* g3    = (const float*)d_in[12];
  const float* mu3   = (const float*)d_in[13];
  const float* sig3  = (const float*)d_in[14];
  const float* root3 = (const float*)d_in[15];
  const float* cb3   = (const float*)d_in[16];
  const float* p1w1  = (const float*)d_in[17];
  const float* p1b1  = (const float*)d_in[18];
  const float* p1w2  = (const float*)d_in[19];
  const float* p1b2  = (const float*)d_in[20];
  const float* p1w3  = (const float*)d_in[21];
  const float* p1b3  = (const float*)d_in[22];
  const float* p2w1  = (const float*)d_in[23];
  const float* p2b1  = (const float*)d_in[24];
  const float* p2w2  = (const float*)d_in[25];
  const float* p2b2  = (const float*)d_in[26];
  const float* p2w3  = (const float*)d_in[27];
  const float* p2b3  = (const float*)d_in[28];

  float* out  = (float*)d_out;
  float* ws   = (float*)d_ws;
  float* x1   = ws;            // 5120*160 = 819200 floats
  float* pos1 = ws + 819200;   // 25600*2  = 51200
  float* x2   = ws + 870400;   // 76800*16 = 1228800
  float* x3   = out;           // 76800
  float* pos2 = out + 76800;   // 76800*2

  conv1_kernel<<<dim3(512), dim3(512), 0, stream>>>(x, pos, g1, mu1, sig1, root1, cb1, x1);
  mlp_kernel<<<dim3(400), dim3(256), 0, stream>>>(pos, x1, p1w1, p1b1, p1w2, p1b2, p1w3, p1b3,
                                                  pos1, 32, 5);
  conv2_kernel<<<dim3(1024), dim3(320), 0, stream>>>(x1, pos1, g2, mu2, sig2, root2, cb2, x2);
  mlp_kernel<<<dim3(1200), dim3(256), 0, stream>>>(pos1, x2, p2w1, p2b1, p2w2, p2b2, p2w3, p2b3,
                                                  pos2, 16, 3);
  conv3_kernel<<<dim3(1024), dim3(384), 0, stream>>>(x2, pos2, g3, mu3, sig3, root3, cb3, x3);
}